// Round 2
// baseline (259.897 us; speedup 1.0000x reference)
//
#include <hip/hip_runtime.h>
#include <hip/hip_bf16.h>
#include <math.h>

typedef unsigned int u32;
typedef unsigned short u16;
typedef __attribute__((ext_vector_type(4))) float f32x4;
typedef __attribute__((ext_vector_type(8))) short bf16x8;

#define D_MODEL 1024
#define SEQ     2048
#define NH      16
#define DH      64
#define MTOT    4096

// 1/sqrt(64) * log2(e): folded into Q so softmax uses exp2
#define QK_SCALE (0.125f * 1.44269504088896340736f)

__device__ __forceinline__ u16 f2bf(float f) {
  union { float f; u32 u; } a; a.f = f;
  u32 r = a.u + 0x7fffu + ((a.u >> 16) & 1u);  // RNE
  return (u16)(r >> 16);
}

__device__ __forceinline__ void async_copy16(const void* g, void* l) {
  __builtin_amdgcn_global_load_lds(
      (const __attribute__((address_space(1))) u32*)g,
      (__attribute__((address_space(3))) u32*)l, 16, 0, 0);
}

// ---------------- fp32 -> bf16 conversion of x and weights ----------------
__global__ __launch_bounds__(256) void k_convert(
    const float* __restrict__ x,  const float* __restrict__ wq,
    const float* __restrict__ wk, const float* __restrict__ wv,
    const float* __restrict__ wo,
    u16* __restrict__ xb,  u16* __restrict__ wqb, u16* __restrict__ wkb,
    u16* __restrict__ wvb, u16* __restrict__ wob) {
  const long NX = (long)MTOT * D_MODEL / 8;     // 524288 groups of 8
  const long NW = (long)D_MODEL * D_MODEL / 8;  // 131072
  long i = (long)blockIdx.x * 256 + threadIdx.x;
  const float* src; u16* dst;
  if (i < NX)               { src = x;  dst = xb;  }
  else if (i < NX + NW)     { src = wq; dst = wqb; i -= NX; }
  else if (i < NX + 2*NW)   { src = wk; dst = wkb; i -= NX + 2*NW - NW; }
  else if (i < NX + 3*NW)   { src = wv; dst = wvb; i -= NX + 2*NW; }
  else                      { src = wo; dst = wob; i -= NX + 3*NW; }
  const f32x4* s4 = (const f32x4*)src + i * 2;
  f32x4 a = s4[0], b = s4[1];
  union { bf16x8 v; u16 e[8]; } o;
  o.e[0] = f2bf(a[0]); o.e[1] = f2bf(a[1]); o.e[2] = f2bf(a[2]); o.e[3] = f2bf(a[3]);
  o.e[4] = f2bf(b[0]); o.e[5] = f2bf(b[1]); o.e[6] = f2bf(b[2]); o.e[7] = f2bf(b[3]);
  *(bf16x8*)(dst + i * 8) = o.v;
}

// ---------------- shared 128x128 GEMM core (C = A * B^T), bf16, BK=32 -----
// A: [M][1024] bf16 row-major, Bm: [N][1024] bf16 row-major (the B^T layout).
// m97 structure: global_load_lds(16B) staging, linear LDS [128][32] (b128
// frag reads are bank-uniform at 64B row stride), 16 MFMA / K-step / wave.
__device__ __forceinline__ void gemm_core(
    const u16* __restrict__ A, const u16* __restrict__ Bm,
    u16* As, u16* Bs, f32x4 acc[4][4], int m0, int n0) {
  const int t = threadIdx.x;
  const int lane = t & 63, w = t >> 6;
  const int wr = (w >> 1) * 64, wc = (w & 1) * 64;  // wave sub-tile 64x64
  const int lr = lane & 15, g = lane >> 4;
  const int rr = t >> 2, c8 = (t & 3) * 8;          // staging row/chunk
#pragma unroll
  for (int mi = 0; mi < 4; ++mi)
#pragma unroll
    for (int ni = 0; ni < 4; ++ni)
      acc[mi][ni] = (f32x4){0.f, 0.f, 0.f, 0.f};
  const u16* ga0 = A  + (size_t)(m0 + rr) * D_MODEL + c8;
  const u16* ga1 = A  + (size_t)(m0 + 64 + rr) * D_MODEL + c8;
  const u16* gb0 = Bm + (size_t)(n0 + rr) * D_MODEL + c8;
  const u16* gb1 = Bm + (size_t)(n0 + 64 + rr) * D_MODEL + c8;
  for (int k0 = 0; k0 < D_MODEL; k0 += 32) {
    async_copy16(ga0 + k0, As + t * 8);
    async_copy16(ga1 + k0, As + 2048 + t * 8);
    async_copy16(gb0 + k0, Bs + t * 8);
    async_copy16(gb1 + k0, Bs + 2048 + t * 8);
    __syncthreads();  // compiler drains vmcnt(0) before s_barrier
    bf16x8 af[4], bfr[4];
#pragma unroll
    for (int mi = 0; mi < 4; ++mi)
      af[mi] = *(const bf16x8*)(As + (wr + mi * 16 + lr) * 32 + g * 8);
#pragma unroll
    for (int ni = 0; ni < 4; ++ni)
      bfr[ni] = *(const bf16x8*)(Bs + (wc + ni * 16 + lr) * 32 + g * 8);
#pragma unroll
    for (int mi = 0; mi < 4; ++mi)
#pragma unroll
      for (int ni = 0; ni < 4; ++ni)
        acc[mi][ni] = __builtin_amdgcn_mfma_f32_16x16x32_bf16(
            af[mi], bfr[ni], acc[mi][ni], 0, 0, 0);
    __syncthreads();
  }
}

// ---------------- fused QKV projection ------------------------------------
// Grid (32, 24): n-tiles 0..7 -> Q, 8..15 -> K, 16..23 -> V.
// Writes [b,h,s,d] bf16 per projection; Q pre-scaled by QK_SCALE.
__global__ __launch_bounds__(256) void k_gemm_qkv(
    const u16* __restrict__ xb, const u16* __restrict__ wqb,
    const u16* __restrict__ wkb, const u16* __restrict__ wvb,
    u16* __restrict__ Qo, u16* __restrict__ Ko, u16* __restrict__ Vo) {
  __shared__ u16 As[128 * 32], Bs[128 * 32];
  const int m0 = blockIdx.x * 128;
  const int n0g = blockIdx.y * 128;
  const int proj = n0g >> 10;       // 0,1,2
  const int n0 = n0g & 1023;
  const u16* Bm = (proj == 0) ? wqb : (proj == 1) ? wkb : wvb;
  u16* Out      = (proj == 0) ? Qo  : (proj == 1) ? Ko  : Vo;
  const float scale = (proj == 0) ? QK_SCALE : 1.0f;
  f32x4 acc[4][4];
  gemm_core(xb, Bm, As, Bs, acc, m0, n0);
  const int t = threadIdx.x, lane = t & 63, w = t >> 6;
  const int wr = (w >> 1) * 64, wc = (w & 1) * 64;
  const int lr = lane & 15, g = lane >> 4;
#pragma unroll
  for (int mi = 0; mi < 4; ++mi)
#pragma unroll
    for (int ni = 0; ni < 4; ++ni)
#pragma unroll
      for (int jj = 0; jj < 4; ++jj) {
        int m = m0 + wr + mi * 16 + 4 * g + jj;    // (b,s)
        int cn = n0 + wc + ni * 16 + lr;           // (h,d)
        int h = cn >> 6, d = cn & 63;
        int b = m >> 11, s = m & 2047;
        Out[(((size_t)(b * NH + h) * SEQ) + s) * DH + d] =
            f2bf(acc[mi][ni][jj] * scale);
      }
}

// ---------------- flash attention (causal) --------------------------------
// Block = 4 waves x 32 q-rows (QBLK=128), KVBLK=32, swapped QK^T so softmax
// is in-register; K/V staged via global_load_lds with pre-swizzled source
// (XOR (row&7)<<4) so b128 frag reads are bank-conflict-free.
__global__ __launch_bounds__(256) void k_attn(
    const u16* __restrict__ Q, const u16* __restrict__ K,
    const u16* __restrict__ V, u16* __restrict__ att) {
  __shared__ u16 Ksh[32 * 64], Vsh[32 * 64];
  const int t = threadIdx.x, lane = t & 63, w = t >> 6;
  const int lr = lane & 15, g = lane >> 4;
  const int qb = blockIdx.x, bh = blockIdx.y;
  const int q0 = qb * 128, qw = q0 + w * 32;
  const size_t hb = (size_t)bh * SEQ * DH;
  const u16* Qp = Q + hb;
  const u16* Kp = K + hb;
  const u16* Vp = V + hb;

  // Q B-fragments hoisted to registers: lane holds Q[qw+nf*16+lr][kk*32+8g..+7]
  bf16x8 qfr[2][2];
#pragma unroll
  for (int nf = 0; nf < 2; ++nf)
#pragma unroll
    for (int kk = 0; kk < 2; ++kk)
      qfr[nf][kk] = *(const bf16x8*)(Qp + (size_t)(qw + nf * 16 + lr) * DH + kk * 32 + g * 8);

  f32x4 o[2][4];
#pragma unroll
  for (int a = 0; a < 2; ++a)
#pragma unroll
    for (int d = 0; d < 4; ++d) o[a][d] = (f32x4){0.f, 0.f, 0.f, 0.f};
  float mrow[2] = {-__builtin_inff(), -__builtin_inff()};
  float lrow[2] = {0.f, 0.f};

  const int nkv = (q0 + 128) >> 5;
  const int swz = (t * 16) ^ (((t >> 3) & 7) << 4);  // pre-swizzled source off

  for (int it = 0; it < nkv; ++it) {
    const int kv0 = it * 32;
    async_copy16((const char*)(Kp + (size_t)kv0 * DH) + swz, (char*)Ksh + t * 16);
    async_copy16((const char*)(Vp + (size_t)kv0 * DH) + swz, (char*)Vsh + t * 16);
    __syncthreads();
    if (kv0 <= qw + 31) {  // wave-uniform causal early-out
      // K A-fragments (swizzled read)
      bf16x8 kfr[2][2];
#pragma unroll
      for (int mf = 0; mf < 2; ++mf) {
        int row = mf * 16 + lr;
#pragma unroll
        for (int kk = 0; kk < 2; ++kk) {
          int off = (row * 128 + (kk * 32 + g * 8) * 2) ^ ((row & 7) << 4);
          kfr[mf][kk] = *(const bf16x8*)((const char*)Ksh + off);
        }
      }
      // S^T = K Q^T : rows kv (mf), cols q (nf)
      f32x4 st[2][2];
#pragma unroll
      for (int mf = 0; mf < 2; ++mf)
#pragma unroll
        for (int nf = 0; nf < 2; ++nf) {
          f32x4 z = (f32x4){0.f, 0.f, 0.f, 0.f};
          z = __builtin_amdgcn_mfma_f32_16x16x32_bf16(kfr[mf][0], qfr[nf][0], z, 0, 0, 0);
          st[mf][nf] = __builtin_amdgcn_mfma_f32_16x16x32_bf16(kfr[mf][1], qfr[nf][1], z, 0, 0, 0);
        }
      if (kv0 + 31 > qw) {  // diagonal block: per-element causal mask
#pragma unroll
        for (int mf = 0; mf < 2; ++mf)
#pragma unroll
          for (int nf = 0; nf < 2; ++nf)
#pragma unroll
            for (int jj = 0; jj < 4; ++jj) {
              int kv = kv0 + mf * 16 + 4 * g + jj;
              int q = qw + nf * 16 + lr;
              st[mf][nf][jj] = (kv > q) ? -__builtin_inff() : st[mf][nf][jj];
            }
      }
      // online softmax over kv (row dim of S^T); state indexed by q = nf*16+lr
      float fac[2];
#pragma unroll
      for (int nf = 0; nf < 2; ++nf) {
        float v = fmaxf(fmaxf(fmaxf(st[0][nf][0], st[0][nf][1]), fmaxf(st[0][nf][2], st[0][nf][3])),
                        fmaxf(fmaxf(st[1][nf][0], st[1][nf][1]), fmaxf(st[1][nf][2], st[1][nf][3])));
        v = fmaxf(v, __shfl_xor(v, 16));
        v = fmaxf(v, __shfl_xor(v, 32));
        float mnew = fmaxf(mrow[nf], v);
        fac[nf] = exp2f(mrow[nf] - mnew);
        mrow[nf] = mnew;
      }
      float p[2][2][4];
#pragma unroll
      for (int mf = 0; mf < 2; ++mf)
#pragma unroll
        for (int nf = 0; nf < 2; ++nf)
#pragma unroll
          for (int jj = 0; jj < 4; ++jj)
            p[mf][nf][jj] = exp2f(st[mf][nf][jj] - mrow[nf]);
#pragma unroll
      for (int nf = 0; nf < 2; ++nf) {
        float sum = ((p[0][nf][0] + p[0][nf][1]) + (p[0][nf][2] + p[0][nf][3])) +
                    ((p[1][nf][0] + p[1][nf][1]) + (p[1][nf][2] + p[1][nf][3]));
        sum += __shfl_xor(sum, 16);
        sum += __shfl_xor(sum, 32);
        lrow[nf] = lrow[nf] * fac[nf] + sum;
      }
      // rescale O: factor for row-position q = 16*qf + 4g + jj lives at lane (4g+jj)
      float fq[2][4];
#pragma unroll
      for (int qf = 0; qf < 2; ++qf)
#pragma unroll
        for (int jj = 0; jj < 4; ++jj)
          fq[qf][jj] = __shfl(fac[qf], 4 * g + jj);
#pragma unroll
      for (int qf = 0; qf < 2; ++qf)
#pragma unroll
        for (int d = 0; d < 4; ++d)
#pragma unroll
          for (int jj = 0; jj < 4; ++jj)
            o[qf][d][jj] *= fq[qf][jj];
      // P -> bf16 A-fragments; k-mapping j'=(mf*4+jj) <-> kv=16mf+4g+jj
      bf16x8 pa[2];
#pragma unroll
      for (int qf = 0; qf < 2; ++qf)
#pragma unroll
        for (int mf = 0; mf < 2; ++mf)
#pragma unroll
          for (int jj = 0; jj < 4; ++jj)
            pa[qf][mf * 4 + jj] = (short)f2bf(p[mf][qf][jj]);
      // V B-fragments with the SAME k-mapping (scalar swizzled reads, 2-way free)
      bf16x8 vb[4];
#pragma unroll
      for (int d = 0; d < 4; ++d)
#pragma unroll
        for (int mf = 0; mf < 2; ++mf)
#pragma unroll
          for (int jj = 0; jj < 4; ++jj) {
            int kv = mf * 16 + 4 * g + jj;
            int off = (kv * 128 + (d * 16 + lr) * 2) ^ ((kv & 7) << 4);
            vb[d][mf * 4 + jj] = *(const short*)((const char*)Vsh + off);
          }
#pragma unroll
      for (int qf = 0; qf < 2; ++qf)
#pragma unroll
        for (int d = 0; d < 4; ++d)
          o[qf][d] = __builtin_amdgcn_mfma_f32_16x16x32_bf16(pa[qf], vb[d], o[qf][d], 0, 0, 0);
    }
    __syncthreads();
  }
  // epilogue: divide by l, write att[b, q, h*64+d] bf16
  float li[2][4];
#pragma unroll
  for (int qf = 0; qf < 2; ++qf)
#pragma unroll
    for (int jj = 0; jj < 4; ++jj)
      li[qf][jj] = 1.0f / __shfl(lrow[qf], 4 * g + jj);
  const int b = bh >> 4, h = bh & 15;
#pragma unroll
  for (int qf = 0; qf < 2; ++qf)
#pragma unroll
    for (int d = 0; d < 4; ++d)
#pragma unroll
      for (int jj = 0; jj < 4; ++jj) {
        int q = qw + qf * 16 + 4 * g + jj;
        int cn = h * 64 + d * 16 + lr;
        att[(size_t)(b * SEQ + q) * D_MODEL + cn] = f2bf(o[qf][d][jj] * li[qf][jj]);
      }
}

// ---------------- output projection (fp32 out) ----------------------------
__global__ __launch_bounds__(256) void k_gemm_out(
    const u16* __restrict__ att, const u16* __restrict__ wob,
    float* __restrict__ out) {
  __shared__ u16 As[128 * 32], Bs[128 * 32];
  const int m0 = blockIdx.x * 128, n0 = blockIdx.y * 128;
  f32x4 acc[4][4];
  gemm_core(att, wob, As, Bs, acc, m0, n0);
  const int t = threadIdx.x, lane = t & 63, w = t >> 6;
  const int wr = (w >> 1) * 64, wc = (w & 1) * 64;
  const int lr = lane & 15, g = lane >> 4;
#pragma unroll
  for (int mi = 0; mi < 4; ++mi)
#pragma unroll
    for (int ni = 0; ni < 4; ++ni)
#pragma unroll
      for (int jj = 0; jj < 4; ++jj) {
        int m = m0 + wr + mi * 16 + 4 * g + jj;
        int n = n0 + wc + ni * 16 + lr;
        out[(size_t)m * D_MODEL + n] = acc[mi][ni][jj];
      }
}

extern "C" void kernel_launch(void* const* d_in, const int* in_sizes, int n_in,
                              void* d_out, int out_size, void* d_ws, size_t ws_size,
                              hipStream_t stream) {
  (void)in_sizes; (void)n_in; (void)out_size; (void)ws_size;
  const float* x  = (const float*)d_in[0];
  const float* WQ = (const float*)d_in[1];
  const float* WK = (const float*)d_in[2];
  const float* WV = (const float*)d_in[3];
  const float* WO = (const float*)d_in[4];
  float* out = (float*)d_out;
  char* ws = (char*)d_ws;
  u16* xb  = (u16*)(ws);
  u16* wqb = (u16*)(ws + ((size_t)8 << 20));
  u16* wkb = (u16*)(ws + ((size_t)10 << 20));
  u16* wvb = (u16*)(ws + ((size_t)12 << 20));
  u16* wob = (u16*)(ws + ((size_t)14 << 20));
  u16* Qb  = (u16*)(ws + ((size_t)16 << 20));
  u16* Kb  = (u16*)(ws + ((size_t)24 << 20));
  u16* Vb  = (u16*)(ws + ((size_t)32 << 20));
  u16* att = (u16*)(ws + ((size_t)40 << 20));

  hipLaunchKernelGGL(k_convert, dim3(4096), dim3(256), 0, stream,
                     x, WQ, WK, WV, WO, xb, wqb, wkb, wvb, wob);
  hipLaunchKernelGGL(k_gemm_qkv, dim3(32, 24), dim3(256), 0, stream,
                     xb, wqb, wkb, wvb, Qb, Kb, Vb);
  hipLaunchKernelGGL(k_attn, dim3(16, 32), dim3(256), 0, stream,
                     Qb, Kb, Vb, att);
  hipLaunchKernelGGL(k_gemm_out, dim3(32, 8), dim3(256), 0, stream,
                     att, wob, out);
}

// Round 5
// 232.186 us; speedup vs baseline: 1.1193x; 1.1193x over previous
//
#include <hip/hip_runtime.h>
#include <hip/hip_bf16.h>
#include <math.h>

typedef unsigned int u32;
typedef unsigned short u16;
typedef __attribute__((ext_vector_type(4))) float f32x4;
typedef __attribute__((ext_vector_type(8))) short bf16x8;

#define D_MODEL 1024
#define SEQ     2048
#define NH      16
#define DH      64
#define MTOT    4096

// 1/sqrt(64) * log2(e): folded into Q so softmax uses exp2
#define QK_SCALE (0.125f * 1.44269504088896340736f)

__device__ __forceinline__ u16 f2bf(float f) {
  union { float f; u32 u; } a; a.f = f;
  u32 r = a.u + 0x7fffu + ((a.u >> 16) & 1u);  // RNE
  return (u16)(r >> 16);
}

__device__ __forceinline__ void async_copy16(const void* g, void* l) {
  __builtin_amdgcn_global_load_lds(
      (const __attribute__((address_space(1))) u32*)g,
      (__attribute__((address_space(3))) u32*)l, 16, 0, 0);
}

// ---------------- fp32 -> bf16 conversion of x and weights ----------------
__global__ __launch_bounds__(256) void k_convert(
    const float* __restrict__ x,  const float* __restrict__ wq,
    const float* __restrict__ wk, const float* __restrict__ wv,
    const float* __restrict__ wo,
    u16* __restrict__ xb,  u16* __restrict__ wqb, u16* __restrict__ wkb,
    u16* __restrict__ wvb, u16* __restrict__ wob) {
  const long NX = (long)MTOT * D_MODEL / 8;     // 524288 groups of 8
  const long NW = (long)D_MODEL * D_MODEL / 8;  // 131072
  long i = (long)blockIdx.x * 256 + threadIdx.x;
  const float* src; u16* dst;
  if (i < NX)               { src = x;  dst = xb;  }
  else if (i < NX + NW)     { src = wq; dst = wqb; i -= NX; }
  else if (i < NX + 2*NW)   { src = wk; dst = wkb; i -= NX + 2*NW - NW; }
  else if (i < NX + 3*NW)   { src = wv; dst = wvb; i -= NX + 2*NW; }
  else                      { src = wo; dst = wob; i -= NX + 3*NW; }
  const f32x4* s4 = (const f32x4*)src + i * 2;
  f32x4 a = s4[0], b = s4[1];
  union { bf16x8 v; u16 e[8]; } o;
  o.e[0] = f2bf(a[0]); o.e[1] = f2bf(a[1]); o.e[2] = f2bf(a[2]); o.e[3] = f2bf(a[3]);
  o.e[4] = f2bf(b[0]); o.e[5] = f2bf(b[1]); o.e[6] = f2bf(b[2]); o.e[7] = f2bf(b[3]);
  *(bf16x8*)(dst + i * 8) = o.v;
}

// ---------------- shared 128x128 GEMM core (C = A * B^T), bf16, BK=32 -----
__device__ __forceinline__ void gemm_core(
    const u16* __restrict__ A, const u16* __restrict__ Bm,
    u16* As, u16* Bs, f32x4 acc[4][4], int m0, int n0) {
  const int t = threadIdx.x;
  const int lane = t & 63, w = t >> 6;
  const int wr = (w >> 1) * 64, wc = (w & 1) * 64;  // wave sub-tile 64x64
  const int lr = lane & 15, g = lane >> 4;
  const int rr = t >> 2, c8 = (t & 3) * 8;          // staging row/chunk
#pragma unroll
  for (int mi = 0; mi < 4; ++mi)
#pragma unroll
    for (int ni = 0; ni < 4; ++ni)
      acc[mi][ni] = (f32x4){0.f, 0.f, 0.f, 0.f};
  const u16* ga0 = A  + (size_t)(m0 + rr) * D_MODEL + c8;
  const u16* ga1 = A  + (size_t)(m0 + 64 + rr) * D_MODEL + c8;
  const u16* gb0 = Bm + (size_t)(n0 + rr) * D_MODEL + c8;
  const u16* gb1 = Bm + (size_t)(n0 + 64 + rr) * D_MODEL + c8;
  for (int k0 = 0; k0 < D_MODEL; k0 += 32) {
    async_copy16(ga0 + k0, As + t * 8);
    async_copy16(ga1 + k0, As + 2048 + t * 8);
    async_copy16(gb0 + k0, Bs + t * 8);
    async_copy16(gb1 + k0, Bs + 2048 + t * 8);
    __syncthreads();
    bf16x8 af[4], bfr[4];
#pragma unroll
    for (int mi = 0; mi < 4; ++mi)
      af[mi] = *(const bf16x8*)(As + (wr + mi * 16 + lr) * 32 + g * 8);
#pragma unroll
    for (int ni = 0; ni < 4; ++ni)
      bfr[ni] = *(const bf16x8*)(Bs + (wc + ni * 16 + lr) * 32 + g * 8);
#pragma unroll
    for (int mi = 0; mi < 4; ++mi)
#pragma unroll
      for (int ni = 0; ni < 4; ++ni)
        acc[mi][ni] = __builtin_amdgcn_mfma_f32_16x16x32_bf16(
            af[mi], bfr[ni], acc[mi][ni], 0, 0, 0);
    __syncthreads();
  }
}

// ---------------- fused QKV projection ------------------------------------
__global__ __launch_bounds__(256) void k_gemm_qkv(
    const u16* __restrict__ xb, const u16* __restrict__ wqb,
    const u16* __restrict__ wkb, const u16* __restrict__ wvb,
    u16* __restrict__ Qo, u16* __restrict__ Ko, u16* __restrict__ Vo) {
  __shared__ u16 As[128 * 32], Bs[128 * 32];
  const int m0 = blockIdx.x * 128;
  const int n0g = blockIdx.y * 128;
  const int proj = n0g >> 10;       // 0,1,2
  const int n0 = n0g & 1023;
  const u16* Bm = (proj == 0) ? wqb : (proj == 1) ? wkb : wvb;
  u16* Out      = (proj == 0) ? Qo  : (proj == 1) ? Ko  : Vo;
  const float scale = (proj == 0) ? QK_SCALE : 1.0f;
  f32x4 acc[4][4];
  gemm_core(xb, Bm, As, Bs, acc, m0, n0);
  const int t = threadIdx.x, lane = t & 63, w = t >> 6;
  const int wr = (w >> 1) * 64, wc = (w & 1) * 64;
  const int lr = lane & 15, g = lane >> 4;
#pragma unroll
  for (int mi = 0; mi < 4; ++mi)
#pragma unroll
    for (int ni = 0; ni < 4; ++ni)
#pragma unroll
      for (int jj = 0; jj < 4; ++jj) {
        int m = m0 + wr + mi * 16 + 4 * g + jj;    // (b,s)
        int cn = n0 + wc + ni * 16 + lr;           // (h,d)
        int h = cn >> 6, d = cn & 63;
        int b = m >> 11, s = m & 2047;
        Out[(((size_t)(b * NH + h) * SEQ) + s) * DH + d] =
            f2bf(acc[mi][ni][jj] * scale);
      }
}

// ---------------- flash attention (causal) --------------------------------
// 4 waves x 32 q-rows (QBLK=128), KVBLK=32, swapped QK^T (in-register
// softmax). Double-buffered K/V staging: one barrier per iter; prefetch of
// tile it+1 issued right after the barrier overlaps with compute of tile it.
// K and V: linear LDS + XOR-(row&7)<<4 pre-swizzled global source (rule #21);
// K frag = b128 swizzled reads, V frag = scalar swizzled reads (round-2
// verified; 2-way bank aliasing is free per m136).
__global__ __launch_bounds__(256) void k_attn(
    const u16* __restrict__ Q, const u16* __restrict__ K,
    const u16* __restrict__ V, u16* __restrict__ att) {
  __shared__ u16 Ksh[2][2048];
  __shared__ u16 Vsh[2][2048];
  const int t = threadIdx.x, lane = t & 63, w = t >> 6;
  const int lr = lane & 15, g = lane >> 4;
  // heavy-first balanced mapping: first 256 blocks = qb 15..8, rest = 7..0
  const int bid = blockIdx.x;
  const int idx = bid & 255;
  const int qb  = (bid < 256) ? (15 - (idx & 7)) : (idx & 7);
  const int bh  = idx >> 3;
  const int q0 = qb * 128, qw = q0 + w * 32;
  const size_t hb = (size_t)bh * SEQ * DH;
  const u16* Qp = Q + hb;
  const u16* Kp = K + hb;
  const u16* Vp = V + hb;

  // Q B-fragments hoisted to registers
  bf16x8 qfr[2][2];
#pragma unroll
  for (int nf = 0; nf < 2; ++nf)
#pragma unroll
    for (int kk = 0; kk < 2; ++kk)
      qfr[nf][kk] = *(const bf16x8*)(Qp + (size_t)(qw + nf * 16 + lr) * DH + kk * 32 + g * 8);

  f32x4 o[2][4];
#pragma unroll
  for (int a = 0; a < 2; ++a)
#pragma unroll
    for (int d = 0; d < 4; ++d) o[a][d] = (f32x4){0.f, 0.f, 0.f, 0.f};
  float mrow[2] = {-__builtin_inff(), -__builtin_inff()};
  float lrow[2] = {0.f, 0.f};

  // pre-swizzled per-thread staging source (rule #21: linear LDS dest,
  // inverse-swizzled global source, swizzled reads) — round-2 verified
  const int swz = (t * 16) ^ (((t >> 3) & 7) << 4);
  const char* srcK = (const char*)Kp + swz;
  const char* srcV = (const char*)Vp + swz;

  const int nkv = (q0 + 128) >> 5;
  int cur = 0;

  // prologue: stage tile 0 into buffer 0
  async_copy16(srcK, (char*)&Ksh[0][0] + t * 16);
  async_copy16(srcV, (char*)&Vsh[0][0] + t * 16);

  for (int it = 0; it < nkv; ++it) {
    const int kv0 = it * 32;
    __syncthreads();  // vmcnt drain -> buf[cur] ready; all waves done with buf[cur^1]
    if (it + 1 < nkv) {  // prefetch next tile into the other buffer
      async_copy16(srcK + (size_t)(it + 1) * 4096, (char*)&Ksh[cur ^ 1][0] + t * 16);
      async_copy16(srcV + (size_t)(it + 1) * 4096, (char*)&Vsh[cur ^ 1][0] + t * 16);
    }
    if (kv0 <= qw + 31) {  // wave-uniform causal early-out
      const char* kbase = (const char*)&Ksh[cur][0];
      const char* vbase = (const char*)&Vsh[cur][0];
      // K A-fragments (swizzled b128 reads)
      bf16x8 kfr[2][2];
#pragma unroll
      for (int mf = 0; mf < 2; ++mf) {
        int row = mf * 16 + lr;
#pragma unroll
        for (int kk = 0; kk < 2; ++kk) {
          int off = (row * 128 + (kk * 32 + g * 8) * 2) ^ ((row & 7) << 4);
          kfr[mf][kk] = *(const bf16x8*)(kbase + off);
        }
      }
      // S^T = K Q^T : rows kv (mf), cols q (nf)
      f32x4 st[2][2];
#pragma unroll
      for (int mf = 0; mf < 2; ++mf)
#pragma unroll
        for (int nf = 0; nf < 2; ++nf) {
          f32x4 z = (f32x4){0.f, 0.f, 0.f, 0.f};
          z = __builtin_amdgcn_mfma_f32_16x16x32_bf16(kfr[mf][0], qfr[nf][0], z, 0, 0, 0);
          st[mf][nf] = __builtin_amdgcn_mfma_f32_16x16x32_bf16(kfr[mf][1], qfr[nf][1], z, 0, 0, 0);
        }
      if (kv0 + 31 > qw) {  // diagonal block: per-element causal mask
#pragma unroll
        for (int mf = 0; mf < 2; ++mf)
#pragma unroll
          for (int nf = 0; nf < 2; ++nf)
#pragma unroll
            for (int jj = 0; jj < 4; ++jj) {
              int kv = kv0 + mf * 16 + 4 * g + jj;
              int q = qw + nf * 16 + lr;
              st[mf][nf][jj] = (kv > q) ? -__builtin_inff() : st[mf][nf][jj];
            }
      }
      // online softmax over kv; state indexed by q = nf*16+lr
      float fac[2];
#pragma unroll
      for (int nf = 0; nf < 2; ++nf) {
        float v = fmaxf(fmaxf(fmaxf(st[0][nf][0], st[0][nf][1]), fmaxf(st[0][nf][2], st[0][nf][3])),
                        fmaxf(fmaxf(st[1][nf][0], st[1][nf][1]), fmaxf(st[1][nf][2], st[1][nf][3])));
        v = fmaxf(v, __shfl_xor(v, 16));
        v = fmaxf(v, __shfl_xor(v, 32));
        float mnew = fmaxf(mrow[nf], v);
        fac[nf] = exp2f(mrow[nf] - mnew);
        mrow[nf] = mnew;
      }
      float p[2][2][4];
#pragma unroll
      for (int mf = 0; mf < 2; ++mf)
#pragma unroll
        for (int nf = 0; nf < 2; ++nf)
#pragma unroll
          for (int jj = 0; jj < 4; ++jj)
            p[mf][nf][jj] = exp2f(st[mf][nf][jj] - mrow[nf]);
#pragma unroll
      for (int nf = 0; nf < 2; ++nf) {
        float sum = ((p[0][nf][0] + p[0][nf][1]) + (p[0][nf][2] + p[0][nf][3])) +
                    ((p[1][nf][0] + p[1][nf][1]) + (p[1][nf][2] + p[1][nf][3]));
        sum += __shfl_xor(sum, 16);
        sum += __shfl_xor(sum, 32);
        lrow[nf] = lrow[nf] * fac[nf] + sum;
      }
      // rescale O: factor for row q = 16*qf + 4g + jj lives at lane (4g+jj)
      float fq[2][4];
#pragma unroll
      for (int qf = 0; qf < 2; ++qf)
#pragma unroll
        for (int jj = 0; jj < 4; ++jj)
          fq[qf][jj] = __shfl(fac[qf], 4 * g + jj);
#pragma unroll
      for (int qf = 0; qf < 2; ++qf)
#pragma unroll
        for (int d = 0; d < 4; ++d)
#pragma unroll
          for (int jj = 0; jj < 4; ++jj)
            o[qf][d][jj] *= fq[qf][jj];
      // P -> bf16 A-fragments; k-slot i <-> kv = 16*(i>>2)+4g+(i&3)
      bf16x8 pa[2];
#pragma unroll
      for (int qf = 0; qf < 2; ++qf)
#pragma unroll
        for (int mf = 0; mf < 2; ++mf)
#pragma unroll
          for (int jj = 0; jj < 4; ++jj)
            pa[qf][mf * 4 + jj] = (short)f2bf(p[mf][qf][jj]);
      // V B-fragments with the SAME k-mapping (scalar swizzled reads,
      // 2-way aliasing free) — round-2 verified path
      bf16x8 vb[4];
#pragma unroll
      for (int d = 0; d < 4; ++d)
#pragma unroll
        for (int mf = 0; mf < 2; ++mf)
#pragma unroll
          for (int jj = 0; jj < 4; ++jj) {
            int kv = mf * 16 + 4 * g + jj;
            int off = (kv * 128 + (d * 16 + lr) * 2) ^ ((kv & 7) << 4);
            vb[d][mf * 4 + jj] = *(const short*)(vbase + off);
          }
#pragma unroll
      for (int qf = 0; qf < 2; ++qf)
#pragma unroll
        for (int d = 0; d < 4; ++d)
          o[qf][d] = __builtin_amdgcn_mfma_f32_16x16x32_bf16(pa[qf], vb[d], o[qf][d], 0, 0, 0);
    }
    cur ^= 1;
  }
  // epilogue: divide by l, write att[b, q, h*64+d] bf16
  float li[2][4];
#pragma unroll
  for (int qf = 0; qf < 2; ++qf)
#pragma unroll
    for (int jj = 0; jj < 4; ++jj)
      li[qf][jj] = 1.0f / __shfl(lrow[qf], 4 * g + jj);
  const int b = bh >> 4, h = bh & 15;
#pragma unroll
  for (int qf = 0; qf < 2; ++qf)
#pragma unroll
    for (int d = 0; d < 4; ++d)
#pragma unroll
      for (int jj = 0; jj < 4; ++jj) {
        int q = qw + qf * 16 + 4 * g + jj;
        int cn = h * 64 + d * 16 + lr;
        att[(size_t)(b * SEQ + q) * D_MODEL + cn] = f2bf(o[qf][d][jj] * li[qf][jj]);
      }
}

// ---------------- output projection (fp32 out) ----------------------------
__global__ __launch_bounds__(256) void k_gemm_out(
    const u16* __restrict__ att, const u16* __restrict__ wob,
    float* __restrict__ out) {
  __shared__ u16 As[128 * 32], Bs[128 * 32];
  const int m0 = blockIdx.x * 128, n0 = blockIdx.y * 128;
  f32x4 acc[4][4];
  gemm_core(att, wob, As, Bs, acc, m0, n0);
  const int t = threadIdx.x, lane = t & 63, w = t >> 6;
  const int wr = (w >> 1) * 64, wc = (w & 1) * 64;
  const int lr = lane & 15, g = lane >> 4;
#pragma unroll
  for (int mi = 0; mi < 4; ++mi)
#pragma unroll
    for (int ni = 0; ni < 4; ++ni)
#pragma unroll
      for (int jj = 0; jj < 4; ++jj) {
        int m = m0 + wr + mi * 16 + 4 * g + jj;
        int n = n0 + wc + ni * 16 + lr;
        out[(size_t)m * D_MODEL + n] = acc[mi][ni][jj];
      }
}

extern "C" void kernel_launch(void* const* d_in, const int* in_sizes, int n_in,
                              void* d_out, int out_size, void* d_ws, size_t ws_size,
                              hipStream_t stream) {
  (void)in_sizes; (void)n_in; (void)out_size; (void)ws_size;
  const float* x  = (const float*)d_in[0];
  const float* WQ = (const float*)d_in[1];
  const float* WK = (const float*)d_in[2];
  const float* WV = (const float*)d_in[3];
  const float* WO = (const float*)d_in[4];
  float* out = (float*)d_out;
  char* ws = (char*)d_ws;
  u16* xb  = (u16*)(ws);
  u16* wqb = (u16*)(ws + ((size_t)8 << 20));
  u16* wkb = (u16*)(ws + ((size_t)10 << 20));
  u16* wvb = (u16*)(ws + ((size_t)12 << 20));
  u16* wob = (u16*)(ws + ((size_t)14 << 20));
  u16* Qb  = (u16*)(ws + ((size_t)16 << 20));
  u16* Kb  = (u16*)(ws + ((size_t)24 << 20));
  u16* Vb  = (u16*)(ws + ((size_t)32 << 20));
  u16* att = (u16*)(ws + ((size_t)40 << 20));

  hipLaunchKernelGGL(k_convert, dim3(4096), dim3(256), 0, stream,
                     x, WQ, WK, WV, WO, xb, wqb, wkb, wvb, wob);
  hipLaunchKernelGGL(k_gemm_qkv, dim3(32, 24), dim3(256), 0, stream,
                     xb, wqb, wkb, wvb, Qb, Kb, Vb);
  hipLaunchKernelGGL(k_attn, dim3(512), dim3(256), 0, stream,
                     Qb, Kb, Vb, att);
  hipLaunchKernelGGL(k_gemm_out, dim3(32, 8), dim3(256), 0, stream,
                     att, wob, out);
}

// Round 6
// 222.521 us; speedup vs baseline: 1.1680x; 1.0434x over previous
//
#include <hip/hip_runtime.h>
#include <hip/hip_bf16.h>
#include <math.h>

typedef unsigned int u32;
typedef unsigned short u16;
typedef __attribute__((ext_vector_type(4))) float f32x4;
typedef __attribute__((ext_vector_type(8))) short bf16x8;

#define D_MODEL 1024
#define SEQ     2048
#define NH      16
#define DH      64
#define MTOT    4096

// 1/sqrt(64) * log2(e): folded into Q so softmax uses exp2
#define QK_SCALE (0.125f * 1.44269504088896340736f)

__device__ __forceinline__ u16 f2bf(float f) {
  union { float f; u32 u; } a; a.f = f;
  u32 r = a.u + 0x7fffu + ((a.u >> 16) & 1u);  // RNE
  return (u16)(r >> 16);
}

__device__ __forceinline__ void async_copy16(const void* g, void* l) {
  __builtin_amdgcn_global_load_lds(
      (const __attribute__((address_space(1))) u32*)g,
      (__attribute__((address_space(3))) u32*)l, 16, 0, 0);
}

// ---------------- fp32 -> bf16 conversion of x and weights ----------------
__global__ __launch_bounds__(256) void k_convert(
    const float* __restrict__ x,  const float* __restrict__ wq,
    const float* __restrict__ wk, const float* __restrict__ wv,
    const float* __restrict__ wo,
    u16* __restrict__ xb,  u16* __restrict__ wqb, u16* __restrict__ wkb,
    u16* __restrict__ wvb, u16* __restrict__ wob) {
  const long NX = (long)MTOT * D_MODEL / 8;     // 524288 groups of 8
  const long NW = (long)D_MODEL * D_MODEL / 8;  // 131072
  long i = (long)blockIdx.x * 256 + threadIdx.x;
  const float* src; u16* dst;
  if (i < NX)               { src = x;  dst = xb;  }
  else if (i < NX + NW)     { src = wq; dst = wqb; i -= NX; }
  else if (i < NX + 2*NW)   { src = wk; dst = wkb; i -= NX + 2*NW - NW; }
  else if (i < NX + 3*NW)   { src = wv; dst = wvb; i -= NX + 2*NW; }
  else                      { src = wo; dst = wob; i -= NX + 3*NW; }
  const f32x4* s4 = (const f32x4*)src + i * 2;
  f32x4 a = s4[0], b = s4[1];
  union { bf16x8 v; u16 e[8]; } o;
  o.e[0] = f2bf(a[0]); o.e[1] = f2bf(a[1]); o.e[2] = f2bf(a[2]); o.e[3] = f2bf(a[3]);
  o.e[4] = f2bf(b[0]); o.e[5] = f2bf(b[1]); o.e[6] = f2bf(b[2]); o.e[7] = f2bf(b[3]);
  *(bf16x8*)(dst + i * 8) = o.v;
}

// ---------------- shared 128x128 GEMM core (C = A * B^T), bf16, BK=32 -----
__device__ __forceinline__ void gemm_core(
    const u16* __restrict__ A, const u16* __restrict__ Bm,
    u16* As, u16* Bs, f32x4 acc[4][4], int m0, int n0) {
  const int t = threadIdx.x;
  const int lane = t & 63, w = t >> 6;
  const int wr = (w >> 1) * 64, wc = (w & 1) * 64;  // wave sub-tile 64x64
  const int lr = lane & 15, g = lane >> 4;
  const int rr = t >> 2, c8 = (t & 3) * 8;          // staging row/chunk
#pragma unroll
  for (int mi = 0; mi < 4; ++mi)
#pragma unroll
    for (int ni = 0; ni < 4; ++ni)
      acc[mi][ni] = (f32x4){0.f, 0.f, 0.f, 0.f};
  const u16* ga0 = A  + (size_t)(m0 + rr) * D_MODEL + c8;
  const u16* ga1 = A  + (size_t)(m0 + 64 + rr) * D_MODEL + c8;
  const u16* gb0 = Bm + (size_t)(n0 + rr) * D_MODEL + c8;
  const u16* gb1 = Bm + (size_t)(n0 + 64 + rr) * D_MODEL + c8;
  for (int k0 = 0; k0 < D_MODEL; k0 += 32) {
    async_copy16(ga0 + k0, As + t * 8);
    async_copy16(ga1 + k0, As + 2048 + t * 8);
    async_copy16(gb0 + k0, Bs + t * 8);
    async_copy16(gb1 + k0, Bs + 2048 + t * 8);
    __syncthreads();
    bf16x8 af[4], bfr[4];
#pragma unroll
    for (int mi = 0; mi < 4; ++mi)
      af[mi] = *(const bf16x8*)(As + (wr + mi * 16 + lr) * 32 + g * 8);
#pragma unroll
    for (int ni = 0; ni < 4; ++ni)
      bfr[ni] = *(const bf16x8*)(Bs + (wc + ni * 16 + lr) * 32 + g * 8);
#pragma unroll
    for (int mi = 0; mi < 4; ++mi)
#pragma unroll
      for (int ni = 0; ni < 4; ++ni)
        acc[mi][ni] = __builtin_amdgcn_mfma_f32_16x16x32_bf16(
            af[mi], bfr[ni], acc[mi][ni], 0, 0, 0);
    __syncthreads();
  }
}

// ---------------- fused QKV projection ------------------------------------
__global__ __launch_bounds__(256) void k_gemm_qkv(
    const u16* __restrict__ xb, const u16* __restrict__ wqb,
    const u16* __restrict__ wkb, const u16* __restrict__ wvb,
    u16* __restrict__ Qo, u16* __restrict__ Ko, u16* __restrict__ Vo) {
  __shared__ u16 As[128 * 32], Bs[128 * 32];
  const int m0 = blockIdx.x * 128;
  const int n0g = blockIdx.y * 128;
  const int proj = n0g >> 10;       // 0,1,2
  const int n0 = n0g & 1023;
  const u16* Bm = (proj == 0) ? wqb : (proj == 1) ? wkb : wvb;
  u16* Out      = (proj == 0) ? Qo  : (proj == 1) ? Ko  : Vo;
  const float scale = (proj == 0) ? QK_SCALE : 1.0f;
  f32x4 acc[4][4];
  gemm_core(xb, Bm, As, Bs, acc, m0, n0);
  const int t = threadIdx.x, lane = t & 63, w = t >> 6;
  const int wr = (w >> 1) * 64, wc = (w & 1) * 64;
  const int lr = lane & 15, g = lane >> 4;
#pragma unroll
  for (int mi = 0; mi < 4; ++mi)
#pragma unroll
    for (int ni = 0; ni < 4; ++ni)
#pragma unroll
      for (int jj = 0; jj < 4; ++jj) {
        int m = m0 + wr + mi * 16 + 4 * g + jj;    // (b,s)
        int cn = n0 + wc + ni * 16 + lr;           // (h,d)
        int h = cn >> 6, d = cn & 63;
        int b = m >> 11, s = m & 2047;
        Out[(((size_t)(b * NH + h) * SEQ) + s) * DH + d] =
            f2bf(acc[mi][ni][jj] * scale);
      }
}

// ---------------- flash attention (causal) --------------------------------
// 4 waves x 16 q-rows (QBLK=64), KVBLK=32, swapped QK^T (in-register
// softmax). 1024 blocks = 4/CU for latency hiding. Double-buffered K/V
// staging: one barrier per iter; prefetch of tile it+1 overlaps compute.
// K and V: linear LDS + XOR-(row&7)<<4 pre-swizzled global source (rule #21);
// K frag = b128 swizzled reads, V frag = scalar swizzled reads (verified).
__global__ __launch_bounds__(256) void k_attn(
    const u16* __restrict__ Q, const u16* __restrict__ K,
    const u16* __restrict__ V, u16* __restrict__ att) {
  __shared__ u16 Ksh[2][2048];
  __shared__ u16 Vsh[2][2048];
  const int t = threadIdx.x, lane = t & 63, w = t >> 6;
  const int lr = lane & 15, g = lane >> 4;
  // heavy-first balanced mapping: first 512 blocks = qb 31..16, rest 15..0
  const int bid = blockIdx.x;
  const int idx = bid & 511;
  const int qb  = (bid < 512) ? (31 - (idx & 15)) : (idx & 15);
  const int bh  = idx >> 4;
  const int q0 = qb * 64, qw = q0 + w * 16;
  const size_t hb = (size_t)bh * SEQ * DH;
  const u16* Qp = Q + hb;
  const u16* Kp = K + hb;
  const u16* Vp = V + hb;

  // Q B-fragments hoisted to registers: lane holds Q[qw+lr][kk*32+8g..+7]
  bf16x8 qfr[2];
#pragma unroll
  for (int kk = 0; kk < 2; ++kk)
    qfr[kk] = *(const bf16x8*)(Qp + (size_t)(qw + lr) * DH + kk * 32 + g * 8);

  f32x4 o[4];
#pragma unroll
  for (int d = 0; d < 4; ++d) o[d] = (f32x4){0.f, 0.f, 0.f, 0.f};
  float mrow = -__builtin_inff();
  float lrow = 0.f;

  // pre-swizzled per-thread staging source (rule #21: linear LDS dest,
  // inverse-swizzled global source, swizzled reads) — verified
  const int swz = (t * 16) ^ (((t >> 3) & 7) << 4);
  const char* srcK = (const char*)Kp + swz;
  const char* srcV = (const char*)Vp + swz;

  const int nkv = (q0 + 64) >> 5;   // = 2*qb + 2
  int cur = 0;

  // prologue: stage tile 0 into buffer 0
  async_copy16(srcK, (char*)&Ksh[0][0] + t * 16);
  async_copy16(srcV, (char*)&Vsh[0][0] + t * 16);

  for (int it = 0; it < nkv; ++it) {
    const int kv0 = it * 32;
    __syncthreads();  // vmcnt drain -> buf[cur] ready; waves done with buf[cur^1]
    if (it + 1 < nkv) {  // prefetch next tile into the other buffer
      async_copy16(srcK + (size_t)(it + 1) * 4096, (char*)&Ksh[cur ^ 1][0] + t * 16);
      async_copy16(srcV + (size_t)(it + 1) * 4096, (char*)&Vsh[cur ^ 1][0] + t * 16);
    }
    if (kv0 <= qw + 15) {  // wave-uniform causal early-out
      const char* kbase = (const char*)&Ksh[cur][0];
      const char* vbase = (const char*)&Vsh[cur][0];
      // K A-fragments (swizzled b128 reads)
      bf16x8 kfr[2][2];
#pragma unroll
      for (int mf = 0; mf < 2; ++mf) {
        int row = mf * 16 + lr;
#pragma unroll
        for (int kk = 0; kk < 2; ++kk) {
          int off = (row * 128 + (kk * 32 + g * 8) * 2) ^ ((row & 7) << 4);
          kfr[mf][kk] = *(const bf16x8*)(kbase + off);
        }
      }
      // S^T = K Q^T : rows kv (mf), col q = lr
      f32x4 st[2];
#pragma unroll
      for (int mf = 0; mf < 2; ++mf) {
        f32x4 z = (f32x4){0.f, 0.f, 0.f, 0.f};
        z = __builtin_amdgcn_mfma_f32_16x16x32_bf16(kfr[mf][0], qfr[0], z, 0, 0, 0);
        st[mf] = __builtin_amdgcn_mfma_f32_16x16x32_bf16(kfr[mf][1], qfr[1], z, 0, 0, 0);
      }
      if (kv0 + 31 > qw) {  // diagonal block: per-element causal mask
#pragma unroll
        for (int mf = 0; mf < 2; ++mf)
#pragma unroll
          for (int jj = 0; jj < 4; ++jj) {
            int kv = kv0 + mf * 16 + 4 * g + jj;
            int q = qw + lr;
            st[mf][jj] = (kv > q) ? -__builtin_inff() : st[mf][jj];
          }
      }
      // online softmax over kv; state indexed by q = lr
      float v = fmaxf(fmaxf(fmaxf(st[0][0], st[0][1]), fmaxf(st[0][2], st[0][3])),
                      fmaxf(fmaxf(st[1][0], st[1][1]), fmaxf(st[1][2], st[1][3])));
      v = fmaxf(v, __shfl_xor(v, 16));
      v = fmaxf(v, __shfl_xor(v, 32));
      float mnew = fmaxf(mrow, v);
      float fac = exp2f(mrow - mnew);
      mrow = mnew;
      float p[2][4];
#pragma unroll
      for (int mf = 0; mf < 2; ++mf)
#pragma unroll
        for (int jj = 0; jj < 4; ++jj)
          p[mf][jj] = exp2f(st[mf][jj] - mrow);
      float sum = ((p[0][0] + p[0][1]) + (p[0][2] + p[0][3])) +
                  ((p[1][0] + p[1][1]) + (p[1][2] + p[1][3]));
      sum += __shfl_xor(sum, 16);
      sum += __shfl_xor(sum, 32);
      lrow = lrow * fac + sum;
      // rescale O: factor for row q = 4g + jj lives at lane (4g+jj)
      float fq[4];
#pragma unroll
      for (int jj = 0; jj < 4; ++jj)
        fq[jj] = __shfl(fac, 4 * g + jj);
#pragma unroll
      for (int d = 0; d < 4; ++d)
#pragma unroll
        for (int jj = 0; jj < 4; ++jj)
          o[d][jj] *= fq[jj];
      // P -> bf16 A-fragment; k-slot i <-> kv = 16*(i>>2)+4g+(i&3)
      bf16x8 pa;
#pragma unroll
      for (int mf = 0; mf < 2; ++mf)
#pragma unroll
        for (int jj = 0; jj < 4; ++jj)
          pa[mf * 4 + jj] = (short)f2bf(p[mf][jj]);
      // V B-fragments with the SAME k-mapping (scalar swizzled reads)
      bf16x8 vb[4];
#pragma unroll
      for (int d = 0; d < 4; ++d)
#pragma unroll
        for (int mf = 0; mf < 2; ++mf)
#pragma unroll
          for (int jj = 0; jj < 4; ++jj) {
            int kv = mf * 16 + 4 * g + jj;
            int off = (kv * 128 + (d * 16 + lr) * 2) ^ ((kv & 7) << 4);
            vb[d][mf * 4 + jj] = *(const short*)(vbase + off);
          }
#pragma unroll
      for (int d = 0; d < 4; ++d)
        o[d] = __builtin_amdgcn_mfma_f32_16x16x32_bf16(pa, vb[d], o[d], 0, 0, 0);
    }
    cur ^= 1;
  }
  // epilogue: divide by l, write att[b, q, h*64+d] bf16
  float li[4];
#pragma unroll
  for (int jj = 0; jj < 4; ++jj)
    li[jj] = 1.0f / __shfl(lrow, 4 * g + jj);
  const int b = bh >> 4, h = bh & 15;
#pragma unroll
  for (int d = 0; d < 4; ++d)
#pragma unroll
    for (int jj = 0; jj < 4; ++jj) {
      int q = qw + 4 * g + jj;
      int cn = h * 64 + d * 16 + lr;
      att[(size_t)(b * SEQ + q) * D_MODEL + cn] = f2bf(o[d][jj] * li[jj]);
    }
}

// ---------------- output projection (fp32 out) ----------------------------
__global__ __launch_bounds__(256) void k_gemm_out(
    const u16* __restrict__ att, const u16* __restrict__ wob,
    float* __restrict__ out) {
  __shared__ u16 As[128 * 32], Bs[128 * 32];
  const int m0 = blockIdx.x * 128, n0 = blockIdx.y * 128;
  f32x4 acc[4][4];
  gemm_core(att, wob, As, Bs, acc, m0, n0);
  const int t = threadIdx.x, lane = t & 63, w = t >> 6;
  const int wr = (w >> 1) * 64, wc = (w & 1) * 64;
  const int lr = lane & 15, g = lane >> 4;
#pragma unroll
  for (int mi = 0; mi < 4; ++mi)
#pragma unroll
    for (int ni = 0; ni < 4; ++ni)
#pragma unroll
      for (int jj = 0; jj < 4; ++jj) {
        int m = m0 + wr + mi * 16 + 4 * g + jj;
        int n = n0 + wc + ni * 16 + lr;
        out[(size_t)m * D_MODEL + n] = acc[mi][ni][jj];
      }
}

extern "C" void kernel_launch(void* const* d_in, const int* in_sizes, int n_in,
                              void* d_out, int out_size, void* d_ws, size_t ws_size,
                              hipStream_t stream) {
  (void)in_sizes; (void)n_in; (void)out_size; (void)ws_size;
  const float* x  = (const float*)d_in[0];
  const float* WQ = (const float*)d_in[1];
  const float* WK = (const float*)d_in[2];
  const float* WV = (const float*)d_in[3];
  const float* WO = (const float*)d_in[4];
  float* out = (float*)d_out;
  char* ws = (char*)d_ws;
  u16* xb  = (u16*)(ws);
  u16* wqb = (u16*)(ws + ((size_t)8 << 20));
  u16* wkb = (u16*)(ws + ((size_t)10 << 20));
  u16* wvb = (u16*)(ws + ((size_t)12 << 20));
  u16* wob = (u16*)(ws + ((size_t)14 << 20));
  u16* Qb  = (u16*)(ws + ((size_t)16 << 20));
  u16* Kb  = (u16*)(ws + ((size_t)24 << 20));
  u16* Vb  = (u16*)(ws + ((size_t)32 << 20));
  u16* att = (u16*)(ws + ((size_t)40 << 20));

  hipLaunchKernelGGL(k_convert, dim3(4096), dim3(256), 0, stream,
                     x, WQ, WK, WV, WO, xb, wqb, wkb, wvb, wob);
  hipLaunchKernelGGL(k_gemm_qkv, dim3(32, 24), dim3(256), 0, stream,
                     xb, wqb, wkb, wvb, Qb, Kb, Vb);
  hipLaunchKernelGGL(k_attn, dim3(1024), dim3(256), 0, stream,
                     Qb, Kb, Vb, att);
  hipLaunchKernelGGL(k_gemm_out, dim3(32, 8), dim3(256), 0, stream,
                     att, wob, out);
}

// Round 8
// 215.224 us; speedup vs baseline: 1.2076x; 1.0339x over previous
//
#include <hip/hip_runtime.h>
#include <hip/hip_bf16.h>
#include <math.h>

typedef unsigned int u32;
typedef unsigned short u16;
typedef __attribute__((ext_vector_type(4))) float f32x4;
typedef __attribute__((ext_vector_type(4))) short bf16x4;
typedef __attribute__((ext_vector_type(8))) short bf16x8;
typedef __attribute__((ext_vector_type(4))) unsigned short u16x4;

#define D_MODEL 1024
#define SEQ     2048
#define NH      16
#define DH      64
#define MTOT    4096

// 1/sqrt(64) * log2(e): folded into Q so softmax uses exp2
#define QK_SCALE (0.125f * 1.44269504088896340736f)

__device__ __forceinline__ u16 f2bf(float f) {
  union { float f; u32 u; } a; a.f = f;
  u32 r = a.u + 0x7fffu + ((a.u >> 16) & 1u);  // RNE
  return (u16)(r >> 16);
}

__device__ __forceinline__ void async_copy16(const void* g, void* l) {
  __builtin_amdgcn_global_load_lds(
      (const __attribute__((address_space(1))) u32*)g,
      (__attribute__((address_space(3))) u32*)l, 16, 0, 0);
}

// ---------------- fp32 -> bf16 conversion of x and weights ----------------
__global__ __launch_bounds__(256) void k_convert(
    const float* __restrict__ x,  const float* __restrict__ wq,
    const float* __restrict__ wk, const float* __restrict__ wv,
    const float* __restrict__ wo,
    u16* __restrict__ xb,  u16* __restrict__ wqb, u16* __restrict__ wkb,
    u16* __restrict__ wvb, u16* __restrict__ wob) {
  const long NX = (long)MTOT * D_MODEL / 8;     // 524288 groups of 8
  const long NW = (long)D_MODEL * D_MODEL / 8;  // 131072
  long i = (long)blockIdx.x * 256 + threadIdx.x;
  const float* src; u16* dst;
  if (i < NX)               { src = x;  dst = xb;  }
  else if (i < NX + NW)     { src = wq; dst = wqb; i -= NX; }
  else if (i < NX + 2*NW)   { src = wk; dst = wkb; i -= NX + 2*NW - NW; }
  else if (i < NX + 3*NW)   { src = wv; dst = wvb; i -= NX + 2*NW; }
  else                      { src = wo; dst = wob; i -= NX + 3*NW; }
  const f32x4* s4 = (const f32x4*)src + i * 2;
  f32x4 a = s4[0], b = s4[1];
  union { bf16x8 v; u16 e[8]; } o;
  o.e[0] = f2bf(a[0]); o.e[1] = f2bf(a[1]); o.e[2] = f2bf(a[2]); o.e[3] = f2bf(a[3]);
  o.e[4] = f2bf(b[0]); o.e[5] = f2bf(b[1]); o.e[6] = f2bf(b[2]); o.e[7] = f2bf(b[3]);
  *(bf16x8*)(dst + i * 8) = o.v;
}

// ---------------- shared 128x128 GEMM core (C = A * B^T), bf16, BK=32 -----
__device__ __forceinline__ void gemm_core(
    const u16* __restrict__ A, const u16* __restrict__ Bm,
    u16* As, u16* Bs, f32x4 acc[4][4], int m0, int n0) {
  const int t = threadIdx.x;
  const int lane = t & 63, w = t >> 6;
  const int wr = (w >> 1) * 64, wc = (w & 1) * 64;  // wave sub-tile 64x64
  const int lr = lane & 15, g = lane >> 4;
  const int rr = t >> 2, c8 = (t & 3) * 8;          // staging row/chunk
#pragma unroll
  for (int mi = 0; mi < 4; ++mi)
#pragma unroll
    for (int ni = 0; ni < 4; ++ni)
      acc[mi][ni] = (f32x4){0.f, 0.f, 0.f, 0.f};
  const u16* ga0 = A  + (size_t)(m0 + rr) * D_MODEL + c8;
  const u16* ga1 = A  + (size_t)(m0 + 64 + rr) * D_MODEL + c8;
  const u16* gb0 = Bm + (size_t)(n0 + rr) * D_MODEL + c8;
  const u16* gb1 = Bm + (size_t)(n0 + 64 + rr) * D_MODEL + c8;
  for (int k0 = 0; k0 < D_MODEL; k0 += 32) {
    async_copy16(ga0 + k0, As + t * 8);
    async_copy16(ga1 + k0, As + 2048 + t * 8);
    async_copy16(gb0 + k0, Bs + t * 8);
    async_copy16(gb1 + k0, Bs + 2048 + t * 8);
    __syncthreads();
    bf16x8 af[4], bfr[4];
#pragma unroll
    for (int mi = 0; mi < 4; ++mi)
      af[mi] = *(const bf16x8*)(As + (wr + mi * 16 + lr) * 32 + g * 8);
#pragma unroll
    for (int ni = 0; ni < 4; ++ni)
      bfr[ni] = *(const bf16x8*)(Bs + (wc + ni * 16 + lr) * 32 + g * 8);
#pragma unroll
    for (int mi = 0; mi < 4; ++mi)
#pragma unroll
      for (int ni = 0; ni < 4; ++ni)
        acc[mi][ni] = __builtin_amdgcn_mfma_f32_16x16x32_bf16(
            af[mi], bfr[ni], acc[mi][ni], 0, 0, 0);
    __syncthreads();
  }
}

// ---------------- fused QKV projection ------------------------------------
// Q,K written [b,h,s,d]; V written TRANSPOSED Vt[b,h,d,s] for k_attn's
// b64 V-fragment reads. Q pre-scaled by QK_SCALE.
__global__ __launch_bounds__(256) void k_gemm_qkv(
    const u16* __restrict__ xb, const u16* __restrict__ wqb,
    const u16* __restrict__ wkb, const u16* __restrict__ wvb,
    u16* __restrict__ Qo, u16* __restrict__ Ko, u16* __restrict__ Vt) {
  __shared__ u16 As[128 * 32], Bs[128 * 32];
  const int m0 = blockIdx.x * 128;
  const int n0g = blockIdx.y * 128;
  const int proj = n0g >> 10;       // 0,1,2
  const int n0 = n0g & 1023;
  const u16* Bm = (proj == 0) ? wqb : (proj == 1) ? wkb : wvb;
  const float scale = (proj == 0) ? QK_SCALE : 1.0f;
  f32x4 acc[4][4];
  gemm_core(xb, Bm, As, Bs, acc, m0, n0);
  const int t = threadIdx.x, lane = t & 63, w = t >> 6;
  const int wr = (w >> 1) * 64, wc = (w & 1) * 64;
  const int lr = lane & 15, g = lane >> 4;
  if (proj != 2) {
    u16* Out = (proj == 0) ? Qo : Ko;
#pragma unroll
    for (int mi = 0; mi < 4; ++mi)
#pragma unroll
      for (int ni = 0; ni < 4; ++ni)
#pragma unroll
        for (int jj = 0; jj < 4; ++jj) {
          int m = m0 + wr + mi * 16 + 4 * g + jj;    // (b,s)
          int cn = n0 + wc + ni * 16 + lr;           // (h,d)
          int h = cn >> 6, d = cn & 63;
          int b = m >> 11, s = m & 2047;
          Out[(((size_t)(b * NH + h) * SEQ) + s) * DH + d] =
              f2bf(acc[mi][ni][jj] * scale);
        }
  } else {
    // Vt[((b*NH+h)*DH + d)*SEQ + s], 4 consecutive s packed per 8B store
#pragma unroll
    for (int mi = 0; mi < 4; ++mi)
#pragma unroll
      for (int ni = 0; ni < 4; ++ni) {
        u16x4 pk;
#pragma unroll
        for (int jj = 0; jj < 4; ++jj) pk[jj] = f2bf(acc[mi][ni][jj]);
        int mb = m0 + wr + mi * 16 + 4 * g;          // s = mb + jj (mb % 4 == 0)
        int cn = n0 + wc + ni * 16 + lr;
        int h = cn >> 6, d = cn & 63;
        int b = mb >> 11, s = mb & 2047;
        *(u16x4*)(Vt + (((size_t)(b * NH + h) * DH + d) * SEQ) + s) = pk;
      }
  }
}

// ---------------- flash attention (causal) --------------------------------
// 4 waves x 16 q-rows (QBLK=64), KVBLK=64. Swapped QK^T (in-register
// softmax). Double-buffered K/Vt staging, one barrier per iter, prefetch of
// tile it+1 overlaps compute of tile it. Grid 1024 = 4 blocks/CU; 4-class
// balanced qb map: each CU's 4 resident blocks sum to 66 kv-iters.
// K LDS [kv=64][d=128B] and Vt LDS [d=64][kv=128B], both XOR-(row&7)<<4
// swizzled via pre-swizzled global source (rule #21, verified form).
// K frags = 8 b128 reads; V frags = 16 b64 reads (jj-contiguous in Vt).
__global__ __launch_bounds__(256, 4) void k_attn(
    const u16* __restrict__ Q, const u16* __restrict__ K,
    const u16* __restrict__ Vt, u16* __restrict__ att) {
  __shared__ u16 Ksh[2][4096];
  __shared__ u16 Vsh[2][4096];
  const int t = threadIdx.x, lane = t & 63, w = t >> 6;
  const int lr = lane & 15, g = lane >> 4;
  // 4-class balanced map: bid = j*256 + bh*8 + k
  const int bid = blockIdx.x;
  const int k4 = bid & 7;
  const int bh = (bid >> 3) & 31;
  const int j4 = bid >> 8;
  const int qb = (j4 == 0) ? k4 : (j4 == 1) ? (15 - k4)
               : (j4 == 2) ? (16 + k4) : (31 - k4);
  const int q0 = qb * 64, qw = q0 + w * 16;
  const size_t hb = (size_t)bh * SEQ * DH;
  const u16* Qp  = Q  + hb;
  const u16* Kp  = K  + hb;
  const u16* Vtp = Vt + hb;   // [d][s] layout, same element count

  // Q B-fragments: lane holds Q[qw+lr][kk*32+8g..+7]
  bf16x8 qfr[2];
#pragma unroll
  for (int kk = 0; kk < 2; ++kk)
    qfr[kk] = *(const bf16x8*)(Qp + (size_t)(qw + lr) * DH + kk * 32 + g * 8);

  f32x4 o[4];
#pragma unroll
  for (int d = 0; d < 4; ++d) o[d] = (f32x4){0.f, 0.f, 0.f, 0.f};
  float mrow = -__builtin_inff();
  float lrow = 0.f;

  // pre-swizzled per-thread staging sources (linear LDS dest t*16)
  const int sswz = ((t & 7) * 16) ^ (((t >> 3) & 7) << 4);
  // K: phys row r=t>>3 (kv), global row stride 128B, tile stride 8192B
  const char* srcK = (const char*)Kp + (t >> 3) * 128 + sswz;
  // Vt: phys row r=t>>3 (d), global row stride SEQ*2=4096B, tile stride 128B
  const char* srcV = (const char*)Vtp + (t >> 3) * 4096 + sswz;

  const int nkv = qb + 1;
  int cur = 0;

  // prologue: stage tile 0 into buffer 0 (two 4KB halves each)
  async_copy16(srcK,          (char*)&Ksh[0][0] + t * 16);
  async_copy16(srcK + 4096,   (char*)&Ksh[0][0] + 4096 + t * 16);   // kv rows 32..63
  async_copy16(srcV,          (char*)&Vsh[0][0] + t * 16);
  async_copy16(srcV + 131072, (char*)&Vsh[0][0] + 4096 + t * 16);   // d rows 32..63

  for (int it = 0; it < nkv; ++it) {
    const int kv0 = it * 64;
    __syncthreads();  // vmcnt drain -> buf[cur] ready; waves done with buf[cur^1]
    if (it + 1 < nkv) {
      const char* sk = srcK + (size_t)(it + 1) * 8192;
      const char* sv = srcV + (size_t)(it + 1) * 128;
      char* kd = (char*)&Ksh[cur ^ 1][0];
      char* vd = (char*)&Vsh[cur ^ 1][0];
      async_copy16(sk,          kd + t * 16);
      async_copy16(sk + 4096,   kd + 4096 + t * 16);
      async_copy16(sv,          vd + t * 16);
      async_copy16(sv + 131072, vd + 4096 + t * 16);
    }
    if (kv0 <= qw + 15) {  // wave-uniform causal early-out
      const char* kbase = (const char*)&Ksh[cur][0];
      const char* vbase = (const char*)&Vsh[cur][0];
      // K A-fragments (swizzled b128 reads), kv rows mf*16+lr
      bf16x8 kfr[4][2];
#pragma unroll
      for (int mf = 0; mf < 4; ++mf) {
        int row = mf * 16 + lr;
#pragma unroll
        for (int kk = 0; kk < 2; ++kk) {
          int off = (row * 128 + kk * 64 + g * 16) ^ ((row & 7) << 4);
          kfr[mf][kk] = *(const bf16x8*)(kbase + off);
        }
      }
      // S^T = K Q^T : rows kv (mf 0..3), col q = lr
      f32x4 st[4];
#pragma unroll
      for (int mf = 0; mf < 4; ++mf) {
        f32x4 z = (f32x4){0.f, 0.f, 0.f, 0.f};
        z = __builtin_amdgcn_mfma_f32_16x16x32_bf16(kfr[mf][0], qfr[0], z, 0, 0, 0);
        st[mf] = __builtin_amdgcn_mfma_f32_16x16x32_bf16(kfr[mf][1], qfr[1], z, 0, 0, 0);
      }
      if (kv0 + 63 > qw) {  // diagonal block: per-element causal mask
#pragma unroll
        for (int mf = 0; mf < 4; ++mf)
#pragma unroll
          for (int jj = 0; jj < 4; ++jj) {
            int kv = kv0 + mf * 16 + 4 * g + jj;
            st[mf][jj] = (kv > qw + lr) ? -__builtin_inff() : st[mf][jj];
          }
      }
      // online softmax over kv; state indexed by q = lr
      float v01 = fmaxf(fmaxf(fmaxf(st[0][0], st[0][1]), fmaxf(st[0][2], st[0][3])),
                        fmaxf(fmaxf(st[1][0], st[1][1]), fmaxf(st[1][2], st[1][3])));
      float v23 = fmaxf(fmaxf(fmaxf(st[2][0], st[2][1]), fmaxf(st[2][2], st[2][3])),
                        fmaxf(fmaxf(st[3][0], st[3][1]), fmaxf(st[3][2], st[3][3])));
      float v = fmaxf(v01, v23);
      v = fmaxf(v, __shfl_xor(v, 16));
      v = fmaxf(v, __shfl_xor(v, 32));
      float mnew = fmaxf(mrow, v);
      float fac = exp2f(mrow - mnew);
      mrow = mnew;
      float p[4][4];
      float sum = 0.f;
#pragma unroll
      for (int mf = 0; mf < 4; ++mf)
#pragma unroll
        for (int jj = 0; jj < 4; ++jj) {
          p[mf][jj] = exp2f(st[mf][jj] - mrow);
          sum += p[mf][jj];
        }
      sum += __shfl_xor(sum, 16);
      sum += __shfl_xor(sum, 32);
      lrow = lrow * fac + sum;
      // rescale O: factor for row q = 4g + jj lives at lane (4g+jj)
      float fq[4];
#pragma unroll
      for (int jj = 0; jj < 4; ++jj)
        fq[jj] = __shfl(fac, 4 * g + jj);
#pragma unroll
      for (int d = 0; d < 4; ++d)
#pragma unroll
        for (int jj = 0; jj < 4; ++jj)
          o[d][jj] *= fq[jj];
      // P -> bf16 A-fragments; MFMA ks: slot i <-> kv = ks*32+16*(i>>2)+4g+(i&3)
      bf16x8 pa[2];
#pragma unroll
      for (int ks = 0; ks < 2; ++ks)
#pragma unroll
        for (int m4 = 0; m4 < 2; ++m4)
#pragma unroll
          for (int jj = 0; jj < 4; ++jj)
            pa[ks][m4 * 4 + jj] = (short)f2bf(p[ks * 2 + m4][jj]);
      // V B-fragments from Vt LDS: b64 reads, jj-contiguous; same k-bijection
      // Vt[row=d16*16+lr][kv = ks*32+m4*16+4g+jj] -> byte row*128+ks*64+m4*32+g*8+jj*2
#pragma unroll
      for (int ks = 0; ks < 2; ++ks) {
        bf16x8 vb[4];
#pragma unroll
        for (int dd = 0; dd < 4; ++dd) {
          int row = dd * 16 + lr;
          int sz = (row & 7) << 4;
          union { bf16x8 v8; bf16x4 h[2]; } u;
          u.h[0] = *(const bf16x4*)(vbase + ((row * 128 + ks * 64 + g * 8) ^ sz));
          u.h[1] = *(const bf16x4*)(vbase + ((row * 128 + ks * 64 + 32 + g * 8) ^ sz));
          vb[dd] = u.v8;
        }
#pragma unroll
        for (int dd = 0; dd < 4; ++dd)
          o[dd] = __builtin_amdgcn_mfma_f32_16x16x32_bf16(pa[ks], vb[dd], o[dd], 0, 0, 0);
      }
    }
    cur ^= 1;
  }
  // epilogue: divide by l, write att[b, q, h*64+d] bf16
  float li[4];
#pragma unroll
  for (int jj = 0; jj < 4; ++jj)
    li[jj] = 1.0f / __shfl(lrow, 4 * g + jj);
  const int b = bh >> 4, h = bh & 15;
#pragma unroll
  for (int d = 0; d < 4; ++d)
#pragma unroll
    for (int jj = 0; jj < 4; ++jj) {
      int q = qw + 4 * g + jj;
      int cn = h * 64 + d * 16 + lr;
      att[(size_t)(b * SEQ + q) * D_MODEL + cn] = f2bf(o[d][jj] * li[jj]);
    }
}

// ---------------- output projection (fp32 out) ----------------------------
__global__ __launch_bounds__(256) void k_gemm_out(
    const u16* __restrict__ att, const u16* __restrict__ wob,
    float* __restrict__ out) {
  __shared__ u16 As[128 * 32], Bs[128 * 32];
  const int m0 = blockIdx.x * 128, n0 = blockIdx.y * 128;
  f32x4 acc[4][4];
  gemm_core(att, wob, As, Bs, acc, m0, n0);
  const int t = threadIdx.x, lane = t & 63, w = t >> 6;
  const int wr = (w >> 1) * 64, wc = (w & 1) * 64;
  const int lr = lane & 15, g = lane >> 4;
#pragma unroll
  for (int mi = 0; mi < 4; ++mi)
#pragma unroll
    for (int ni = 0; ni < 4; ++ni)
#pragma unroll
      for (int jj = 0; jj < 4; ++jj) {
        int m = m0 + wr + mi * 16 + 4 * g + jj;
        int n = n0 + wc + ni * 16 + lr;
        out[(size_t)m * D_MODEL + n] = acc[mi][ni][jj];
      }
}

extern "C" void kernel_launch(void* const* d_in, const int* in_sizes, int n_in,
                              void* d_out, int out_size, void* d_ws, size_t ws_size,
                              hipStream_t stream) {
  (void)in_sizes; (void)n_in; (void)out_size; (void)ws_size;
  const float* x  = (const float*)d_in[0];
  const float* WQ = (const float*)d_in[1];
  const float* WK = (const float*)d_in[2];
  const float* WV = (const float*)d_in[3];
  const float* WO = (const float*)d_in[4];
  float* out = (float*)d_out;
  char* ws = (char*)d_ws;
  u16* xb  = (u16*)(ws);
  u16* wqb = (u16*)(ws + ((size_t)8 << 20));
  u16* wkb = (u16*)(ws + ((size_t)10 << 20));
  u16* wvb = (u16*)(ws + ((size_t)12 << 20));
  u16* wob = (u16*)(ws + ((size_t)14 << 20));
  u16* Qb  = (u16*)(ws + ((size_t)16 << 20));
  u16* Kb  = (u16*)(ws + ((size_t)24 << 20));
  u16* Vtb = (u16*)(ws + ((size_t)32 << 20));
  u16* att = (u16*)(ws + ((size_t)40 << 20));

  hipLaunchKernelGGL(k_convert, dim3(4096), dim3(256), 0, stream,
                     x, WQ, WK, WV, WO, xb, wqb, wkb, wvb, wob);
  hipLaunchKernelGGL(k_gemm_qkv, dim3(32, 24), dim3(256), 0, stream,
                     xb, wqb, wkb, wvb, Qb, Kb, Vtb);
  hipLaunchKernelGGL(k_attn, dim3(1024), dim3(256), 0, stream,
                     Qb, Kb, Vtb, att);
  hipLaunchKernelGGL(k_gemm_out, dim3(32, 8), dim3(256), 0, stream,
                     att, wob, out);
}

// Round 11
// 196.066 us; speedup vs baseline: 1.3256x; 1.0977x over previous
//
#include <hip/hip_runtime.h>
#include <hip/hip_bf16.h>
#include <math.h>

typedef unsigned int u32;
typedef unsigned short u16;
typedef __attribute__((ext_vector_type(4))) float f32x4;
typedef __attribute__((ext_vector_type(4))) short bf16x4;
typedef __attribute__((ext_vector_type(8))) short bf16x8;
typedef __attribute__((ext_vector_type(4))) unsigned short u16x4;

#define D_MODEL 1024
#define SEQ     2048
#define NH      16
#define DH      64
#define MTOT    4096

// 1/sqrt(64) * log2(e): folded into Q so softmax uses exp2
#define QK_SCALE (0.125f * 1.44269504088896340736f)

__device__ __forceinline__ u16 f2bf(float f) {
  union { float f; u32 u; } a; a.f = f;
  u32 r = a.u + 0x7fffu + ((a.u >> 16) & 1u);  // RNE
  return (u16)(r >> 16);
}

// packed f32->bf16 RNE convert (T12 primitive; guide recipe operand order)
__device__ __forceinline__ u32 cvtpk(float lo, float hi) {
  u32 r;
  asm("v_cvt_pk_bf16_f32 %0, %1, %2" : "=v"(r) : "v"(lo), "v"(hi));
  return r;
}

__device__ __forceinline__ void async_copy16(const void* g, void* l) {
  __builtin_amdgcn_global_load_lds(
      (const __attribute__((address_space(1))) u32*)g,
      (__attribute__((address_space(3))) u32*)l, 16, 0, 0);
}

// ---------------- fp32 -> bf16 conversion of x and weights ----------------
__global__ __launch_bounds__(256) void k_convert(
    const float* __restrict__ x,  const float* __restrict__ wq,
    const float* __restrict__ wk, const float* __restrict__ wv,
    const float* __restrict__ wo,
    u16* __restrict__ xb,  u16* __restrict__ wqb, u16* __restrict__ wkb,
    u16* __restrict__ wvb, u16* __restrict__ wob) {
  const long NX = (long)MTOT * D_MODEL / 8;     // 524288 groups of 8
  const long NW = (long)D_MODEL * D_MODEL / 8;  // 131072
  long i = (long)blockIdx.x * 256 + threadIdx.x;
  const float* src; u16* dst;
  if (i < NX)               { src = x;  dst = xb;  }
  else if (i < NX + NW)     { src = wq; dst = wqb; i -= NX; }
  else if (i < NX + 2*NW)   { src = wk; dst = wkb; i -= NX + 2*NW - NW; }
  else if (i < NX + 3*NW)   { src = wv; dst = wvb; i -= NX + 2*NW; }
  else                      { src = wo; dst = wob; i -= NX + 3*NW; }
  const f32x4* s4 = (const f32x4*)src + i * 2;
  f32x4 a = s4[0], b = s4[1];
  union { bf16x8 v; u16 e[8]; } o;
  o.e[0] = f2bf(a[0]); o.e[1] = f2bf(a[1]); o.e[2] = f2bf(a[2]); o.e[3] = f2bf(a[3]);
  o.e[4] = f2bf(b[0]); o.e[5] = f2bf(b[1]); o.e[6] = f2bf(b[2]); o.e[7] = f2bf(b[3]);
  *(bf16x8*)(dst + i * 8) = o.v;
}

// ---------------- shared 128x128 GEMM core (C = A * B^T), bf16, BK=32 -----
__device__ __forceinline__ void gemm_core(
    const u16* __restrict__ A, const u16* __restrict__ Bm,
    u16* As, u16* Bs, f32x4 acc[4][4], int m0, int n0) {
  const int t = threadIdx.x;
  const int lane = t & 63, w = t >> 6;
  const int wr = (w >> 1) * 64, wc = (w & 1) * 64;  // wave sub-tile 64x64
  const int lr = lane & 15, g = lane >> 4;
  const int rr = t >> 2, c8 = (t & 3) * 8;          // staging row/chunk
#pragma unroll
  for (int mi = 0; mi < 4; ++mi)
#pragma unroll
    for (int ni = 0; ni < 4; ++ni)
      acc[mi][ni] = (f32x4){0.f, 0.f, 0.f, 0.f};
  const u16* ga0 = A  + (size_t)(m0 + rr) * D_MODEL + c8;
  const u16* ga1 = A  + (size_t)(m0 + 64 + rr) * D_MODEL + c8;
  const u16* gb0 = Bm + (size_t)(n0 + rr) * D_MODEL + c8;
  const u16* gb1 = Bm + (size_t)(n0 + 64 + rr) * D_MODEL + c8;
  for (int k0 = 0; k0 < D_MODEL; k0 += 32) {
    async_copy16(ga0 + k0, As + t * 8);
    async_copy16(ga1 + k0, As + 2048 + t * 8);
    async_copy16(gb0 + k0, Bs + t * 8);
    async_copy16(gb1 + k0, Bs + 2048 + t * 8);
    __syncthreads();
    bf16x8 af[4], bfr[4];
#pragma unroll
    for (int mi = 0; mi < 4; ++mi)
      af[mi] = *(const bf16x8*)(As + (wr + mi * 16 + lr) * 32 + g * 8);
#pragma unroll
    for (int ni = 0; ni < 4; ++ni)
      bfr[ni] = *(const bf16x8*)(Bs + (wc + ni * 16 + lr) * 32 + g * 8);
#pragma unroll
    for (int mi = 0; mi < 4; ++mi)
#pragma unroll
      for (int ni = 0; ni < 4; ++ni)
        acc[mi][ni] = __builtin_amdgcn_mfma_f32_16x16x32_bf16(
            af[mi], bfr[ni], acc[mi][ni], 0, 0, 0);
    __syncthreads();
  }
}

// ---------------- fused QKV projection ------------------------------------
// Q,K written [b,h,s,d]; V written TRANSPOSED Vt[b,h,d,s] for k_attn's
// b64 V-fragment reads. Q pre-scaled by QK_SCALE.
__global__ __launch_bounds__(256) void k_gemm_qkv(
    const u16* __restrict__ xb, const u16* __restrict__ wqb,
    const u16* __restrict__ wkb, const u16* __restrict__ wvb,
    u16* __restrict__ Qo, u16* __restrict__ Ko, u16* __restrict__ Vt) {
  __shared__ u16 As[128 * 32], Bs[128 * 32];
  const int m0 = blockIdx.x * 128;
  const int n0g = blockIdx.y * 128;
  const int proj = n0g >> 10;       // 0,1,2
  const int n0 = n0g & 1023;
  const u16* Bm = (proj == 0) ? wqb : (proj == 1) ? wkb : wvb;
  const float scale = (proj == 0) ? QK_SCALE : 1.0f;
  f32x4 acc[4][4];
  gemm_core(xb, Bm, As, Bs, acc, m0, n0);
  const int t = threadIdx.x, lane = t & 63, w = t >> 6;
  const int wr = (w >> 1) * 64, wc = (w & 1) * 64;
  const int lr = lane & 15, g = lane >> 4;
  if (proj != 2) {
    u16* Out = (proj == 0) ? Qo : Ko;
#pragma unroll
    for (int mi = 0; mi < 4; ++mi)
#pragma unroll
      for (int ni = 0; ni < 4; ++ni)
#pragma unroll
        for (int jj = 0; jj < 4; ++jj) {
          int m = m0 + wr + mi * 16 + 4 * g + jj;    // (b,s)
          int cn = n0 + wc + ni * 16 + lr;           // (h,d)
          int h = cn >> 6, d = cn & 63;
          int b = m >> 11, s = m & 2047;
          Out[(((size_t)(b * NH + h) * SEQ) + s) * DH + d] =
              f2bf(acc[mi][ni][jj] * scale);
        }
  } else {
    // Vt[((b*NH+h)*DH + d)*SEQ + s], 4 consecutive s packed per 8B store
#pragma unroll
    for (int mi = 0; mi < 4; ++mi)
#pragma unroll
      for (int ni = 0; ni < 4; ++ni) {
        u16x4 pk;
#pragma unroll
        for (int jj = 0; jj < 4; ++jj) pk[jj] = f2bf(acc[mi][ni][jj]);
        int mb = m0 + wr + mi * 16 + 4 * g;          // s = mb + jj (mb % 4 == 0)
        int cn = n0 + wc + ni * 16 + lr;
        int h = cn >> 6, d = cn & 63;
        int b = mb >> 11, s = mb & 2047;
        *(u16x4*)(Vt + (((size_t)(b * NH + h) * DH + d) * SEQ) + s) = pk;
      }
  }
}

// ---------------- flash attention (causal) --------------------------------
// 4 waves x 16 q-rows (QBLK=64), KVBLK=64, 4 blocks/CU. Swapped QK^T,
// in-register softmax. Double-buffered K/Vt staging (verified layouts).
// VALU reduction vs round 8: (1) P->bf16 via v_cvt_pk_bf16_f32 (64->8 ops);
// (2) l via MFMA ones-column (kills sum-tree + epilogue shfl; l indexed by
// q=4g+jj like o); (3) defer-max THR=8 skips rescale when max stable.
// Heavy-first class order: heaviest qb dispatched first (shorter drain tail).
__global__ __launch_bounds__(256, 4) void k_attn(
    const u16* __restrict__ Q, const u16* __restrict__ K,
    const u16* __restrict__ Vt, u16* __restrict__ att) {
  __shared__ u16 Ksh[2][4096];
  __shared__ u16 Vsh[2][4096];
  const int t = threadIdx.x, lane = t & 63, w = t >> 6;
  const int lr = lane & 15, g = lane >> 4;
  // 4-class balanced, heavy-first: per-k4 nkv sums = 66
  const int bid = blockIdx.x;
  const int k4 = bid & 7;
  const int bh = (bid >> 3) & 31;
  const int j4 = bid >> 8;
  const int qb = (j4 == 0) ? (31 - k4) : (j4 == 1) ? k4
               : (j4 == 2) ? (23 - k4) : (8 + k4);
  const int q0 = qb * 64, qw = q0 + w * 16;
  const size_t hb = (size_t)bh * SEQ * DH;
  const u16* Qp  = Q  + hb;
  const u16* Kp  = K  + hb;
  const u16* Vtp = Vt + hb;   // [d][s] layout

  // Q B-fragments: lane holds Q[qw+lr][kk*32+8g..+7]
  bf16x8 qfr[2];
#pragma unroll
  for (int kk = 0; kk < 2; ++kk)
    qfr[kk] = *(const bf16x8*)(Qp + (size_t)(qw + lr) * DH + kk * 32 + g * 8);

  f32x4 o[4];
#pragma unroll
  for (int d = 0; d < 4; ++d) o[d] = (f32x4){0.f, 0.f, 0.f, 0.f};
  f32x4 lacc = (f32x4){0.f, 0.f, 0.f, 0.f};   // l for q=qw+4g+jj (same idx as o)
  float mrow = -__builtin_inff();

  // all-ones B fragment for the l-accumulation MFMA
  const short one_bf = (short)0x3F80;
  const bf16x8 onesb = {one_bf, one_bf, one_bf, one_bf,
                        one_bf, one_bf, one_bf, one_bf};

  // pre-swizzled per-thread staging sources (linear LDS dest t*16)
  const int sswz = ((t & 7) * 16) ^ (((t >> 3) & 7) << 4);
  const char* srcK = (const char*)Kp + (t >> 3) * 128 + sswz;
  const char* srcV = (const char*)Vtp + (t >> 3) * 4096 + sswz;

  const int nkv = qb + 1;
  int cur = 0;

  // prologue: stage tile 0 into buffer 0 (two 4KB halves each)
  async_copy16(srcK,          (char*)&Ksh[0][0] + t * 16);
  async_copy16(srcK + 4096,   (char*)&Ksh[0][0] + 4096 + t * 16);
  async_copy16(srcV,          (char*)&Vsh[0][0] + t * 16);
  async_copy16(srcV + 131072, (char*)&Vsh[0][0] + 4096 + t * 16);

  for (int it = 0; it < nkv; ++it) {
    const int kv0 = it * 64;
    __syncthreads();  // vmcnt drain -> buf[cur] ready
    if (it + 1 < nkv) {
      const char* sk = srcK + (size_t)(it + 1) * 8192;
      const char* sv = srcV + (size_t)(it + 1) * 128;
      char* kd = (char*)&Ksh[cur ^ 1][0];
      char* vd = (char*)&Vsh[cur ^ 1][0];
      async_copy16(sk,          kd + t * 16);
      async_copy16(sk + 4096,   kd + 4096 + t * 16);
      async_copy16(sv,          vd + t * 16);
      async_copy16(sv + 131072, vd + 4096 + t * 16);
    }
    if (kv0 <= qw + 15) {  // wave-uniform causal early-out
      const char* kbase = (const char*)&Ksh[cur][0];
      const char* vbase = (const char*)&Vsh[cur][0];
      // K A-fragments (swizzled b128 reads), kv rows mf*16+lr
      bf16x8 kfr[4][2];
#pragma unroll
      for (int mf = 0; mf < 4; ++mf) {
        int row = mf * 16 + lr;
#pragma unroll
        for (int kk = 0; kk < 2; ++kk) {
          int off = (row * 128 + kk * 64 + g * 16) ^ ((row & 7) << 4);
          kfr[mf][kk] = *(const bf16x8*)(kbase + off);
        }
      }
      // S^T = K Q^T : rows kv (mf 0..3), col q = lr
      f32x4 st[4];
#pragma unroll
      for (int mf = 0; mf < 4; ++mf) {
        f32x4 z = (f32x4){0.f, 0.f, 0.f, 0.f};
        z = __builtin_amdgcn_mfma_f32_16x16x32_bf16(kfr[mf][0], qfr[0], z, 0, 0, 0);
        st[mf] = __builtin_amdgcn_mfma_f32_16x16x32_bf16(kfr[mf][1], qfr[1], z, 0, 0, 0);
      }
      if (kv0 + 63 > qw) {  // diagonal block: per-element causal mask
#pragma unroll
        for (int mf = 0; mf < 4; ++mf)
#pragma unroll
          for (int jj = 0; jj < 4; ++jj) {
            int kv = kv0 + mf * 16 + 4 * g + jj;
            st[mf][jj] = (kv > qw + lr) ? -__builtin_inff() : st[mf][jj];
          }
      }
      // tile max over kv for q = lr
      float v01 = fmaxf(fmaxf(fmaxf(st[0][0], st[0][1]), fmaxf(st[0][2], st[0][3])),
                        fmaxf(fmaxf(st[1][0], st[1][1]), fmaxf(st[1][2], st[1][3])));
      float v23 = fmaxf(fmaxf(fmaxf(st[2][0], st[2][1]), fmaxf(st[2][2], st[2][3])),
                        fmaxf(fmaxf(st[3][0], st[3][1]), fmaxf(st[3][2], st[3][3])));
      float v = fmaxf(v01, v23);
      v = fmaxf(v, __shfl_xor(v, 16));
      v = fmaxf(v, __shfl_xor(v, 32));
      // defer-max (T13): rescale only if max grew by > 8 (exp2 domain)
      if (__any(v > mrow + 8.0f)) {
        float mnew = fmaxf(mrow, v);
        float fac = exp2f(mrow - mnew);
        mrow = mnew;
        float fq[4];
#pragma unroll
        for (int jj = 0; jj < 4; ++jj)
          fq[jj] = __shfl(fac, 4 * g + jj);
#pragma unroll
        for (int d = 0; d < 4; ++d)
#pragma unroll
          for (int jj = 0; jj < 4; ++jj)
            o[d][jj] *= fq[jj];
#pragma unroll
        for (int jj = 0; jj < 4; ++jj)
          lacc[jj] *= fq[jj];
      }
      // P = exp2(S - m); bounded by 2^8 when deferred
      float p[4][4];
#pragma unroll
      for (int mf = 0; mf < 4; ++mf)
#pragma unroll
        for (int jj = 0; jj < 4; ++jj)
          p[mf][jj] = exp2f(st[mf][jj] - mrow);
      // P -> bf16 A-fragments via cvt_pk; slot m4*4+jj <- p[ks*2+m4][jj]
      bf16x8 pa[2];
#pragma unroll
      for (int ks = 0; ks < 2; ++ks) {
        union { bf16x8 v8; u32 wdz[4]; } pu;
        pu.wdz[0] = cvtpk(p[ks * 2][0],     p[ks * 2][1]);
        pu.wdz[1] = cvtpk(p[ks * 2][2],     p[ks * 2][3]);
        pu.wdz[2] = cvtpk(p[ks * 2 + 1][0], p[ks * 2 + 1][1]);
        pu.wdz[3] = cvtpk(p[ks * 2 + 1][2], p[ks * 2 + 1][3]);
        pa[ks] = pu.v8;
      }
      // l accumulation on the MFMA pipe: C[q][*] = sum_kv P (B = ones)
      lacc = __builtin_amdgcn_mfma_f32_16x16x32_bf16(pa[0], onesb, lacc, 0, 0, 0);
      lacc = __builtin_amdgcn_mfma_f32_16x16x32_bf16(pa[1], onesb, lacc, 0, 0, 0);
      // V B-fragments from Vt LDS: b64 reads, jj-contiguous
#pragma unroll
      for (int ks = 0; ks < 2; ++ks) {
        bf16x8 vb[4];
#pragma unroll
        for (int dd = 0; dd < 4; ++dd) {
          int row = dd * 16 + lr;
          int sz = (row & 7) << 4;
          union { bf16x8 v8; bf16x4 h[2]; } u;
          u.h[0] = *(const bf16x4*)(vbase + ((row * 128 + ks * 64 + g * 8) ^ sz));
          u.h[1] = *(const bf16x4*)(vbase + ((row * 128 + ks * 64 + 32 + g * 8) ^ sz));
          vb[dd] = u.v8;
        }
#pragma unroll
        for (int dd = 0; dd < 4; ++dd)
          o[dd] = __builtin_amdgcn_mfma_f32_16x16x32_bf16(pa[ks], vb[dd], o[dd], 0, 0, 0);
      }
    }
    cur ^= 1;
  }
  // epilogue: divide by l (lane-local now), write att[b, q, h*64+d] bf16
  const int b = bh >> 4, h = bh & 15;
#pragma unroll
  for (int jj = 0; jj < 4; ++jj) {
    float li = 1.0f / lacc[jj];
    int q = qw + 4 * g + jj;
#pragma unroll
    for (int d = 0; d < 4; ++d) {
      int cn = h * 64 + d * 16 + lr;
      att[(size_t)(b * SEQ + q) * D_MODEL + cn] = f2bf(o[d][jj] * li);
    }
  }
}

// ---------------- output projection (fp32 out) ----------------------------
__global__ __launch_bounds__(256) void k_gemm_out(
    const u16* __restrict__ att, const u16* __restrict__ wob,
    float* __restrict__ out) {
  __shared__ u16 As[128 * 32], Bs[128 * 32];
  const int m0 = blockIdx.x * 128, n0 = blockIdx.y * 128;
  f32x4 acc[4][4];
  gemm_core(att, wob, As, Bs, acc, m0, n0);
  const int t = threadIdx.x, lane = t & 63, w = t >> 6;
  const int wr = (w >> 1) * 64, wc = (w & 1) * 64;
  const int lr = lane & 15, g = lane >> 4;
#pragma unroll
  for (int mi = 0; mi < 4; ++mi)
#pragma unroll
    for (int ni = 0; ni < 4; ++ni)
#pragma unroll
      for (int jj = 0; jj < 4; ++jj) {
        int m = m0 + wr + mi * 16 + 4 * g + jj;
        int n = n0 + wc + ni * 16 + lr;
        out[(size_t)m * D_MODEL + n] = acc[mi][ni][jj];
      }
}

extern "C" void kernel_launch(void* const* d_in, const int* in_sizes, int n_in,
                              void* d_out, int out_size, void* d_ws, size_t ws_size,
                              hipStream_t stream) {
  (void)in_sizes; (void)n_in; (void)out_size; (void)ws_size;
  const float* x  = (const float*)d_in[0];
  const float* WQ = (const float*)d_in[1];
  const float* WK = (const float*)d_in[2];
  const float* WV = (const float*)d_in[3];
  const float* WO = (const float*)d_in[4];
  float* out = (float*)d_out;
  char* ws = (char*)d_ws;
  u16* xb  = (u16*)(ws);
  u16* wqb = (u16*)(ws + ((size_t)8 << 20));
  u16* wkb = (u16*)(ws + ((size_t)10 << 20));
  u16* wvb = (u16*)(ws + ((size_t)12 << 20));
  u16* wob = (u16*)(ws + ((size_t)14 << 20));
  u16* Qb  = (u16*)(ws + ((size_t)16 << 20));
  u16* Kb  = (u16*)(ws + ((size_t)24 << 20));
  u16* Vtb = (u16*)(ws + ((size_t)32 << 20));
  u16* att = (u16*)(ws + ((size_t)40 << 20));

  hipLaunchKernelGGL(k_convert, dim3(4096), dim3(256), 0, stream,
                     x, WQ, WK, WV, WO, xb, wqb, wkb, wvb, wob);
  hipLaunchKernelGGL(k_gemm_qkv, dim3(32, 24), dim3(256), 0, stream,
                     xb, wqb, wkb, wvb, Qb, Kb, Vtb);
  hipLaunchKernelGGL(k_attn, dim3(1024), dim3(256), 0, stream,
                     Qb, Kb, Vtb, att);
  hipLaunchKernelGGL(k_gemm_out, dim3(32, 8), dim3(256), 0, stream,
                     att, wob, out);
}

// Round 13
// 181.918 us; speedup vs baseline: 1.4286x; 1.0778x over previous
//
#include <hip/hip_runtime.h>
#include <hip/hip_bf16.h>
#include <math.h>

typedef unsigned int u32;
typedef unsigned short u16;
typedef __attribute__((ext_vector_type(4))) float f32x4;
typedef __attribute__((ext_vector_type(4))) short bf16x4;
typedef __attribute__((ext_vector_type(8))) short bf16x8;
typedef __attribute__((ext_vector_type(4))) unsigned short u16x4;

#define D_MODEL 1024
#define SEQ     2048
#define NH      16
#define DH      64
#define MTOT    4096

// 1/sqrt(64) * log2(e): folded into Q so softmax uses exp2
#define QK_SCALE (0.125f * 1.44269504088896340736f)

__device__ __forceinline__ u16 f2bf(float f) {
  union { float f; u32 u; } a; a.f = f;
  u32 r = a.u + 0x7fffu + ((a.u >> 16) & 1u);  // RNE
  return (u16)(r >> 16);
}

// packed f32->bf16 RNE convert (T12 primitive)
__device__ __forceinline__ u32 cvtpk(float lo, float hi) {
  u32 r;
  asm("v_cvt_pk_bf16_f32 %0, %1, %2" : "=v"(r) : "v"(lo), "v"(hi));
  return r;
}

__device__ __forceinline__ void async_copy16(const void* g, void* l) {
  __builtin_amdgcn_global_load_lds(
      (const __attribute__((address_space(1))) u32*)g,
      (__attribute__((address_space(3))) u32*)l, 16, 0, 0);
}

// ---------------- fp32 -> bf16 conversion of x and weights ----------------
__global__ __launch_bounds__(256) void k_convert(
    const float* __restrict__ x,  const float* __restrict__ wq,
    const float* __restrict__ wk, const float* __restrict__ wv,
    const float* __restrict__ wo,
    u16* __restrict__ xb,  u16* __restrict__ wqb, u16* __restrict__ wkb,
    u16* __restrict__ wvb, u16* __restrict__ wob) {
  const long NX = (long)MTOT * D_MODEL / 8;     // 524288 groups of 8
  const long NW = (long)D_MODEL * D_MODEL / 8;  // 131072
  long i = (long)blockIdx.x * 256 + threadIdx.x;
  const float* src; u16* dst;
  if (i < NX)               { src = x;  dst = xb;  }
  else if (i < NX + NW)     { src = wq; dst = wqb; i -= NX; }
  else if (i < NX + 2*NW)   { src = wk; dst = wkb; i -= NX + 2*NW - NW; }
  else if (i < NX + 3*NW)   { src = wv; dst = wvb; i -= NX + 2*NW; }
  else                      { src = wo; dst = wob; i -= NX + 3*NW; }
  const f32x4* s4 = (const f32x4*)src + i * 2;
  f32x4 a = s4[0], b = s4[1];
  union { bf16x8 v; u16 e[8]; } o;
  o.e[0] = f2bf(a[0]); o.e[1] = f2bf(a[1]); o.e[2] = f2bf(a[2]); o.e[3] = f2bf(a[3]);
  o.e[4] = f2bf(b[0]); o.e[5] = f2bf(b[1]); o.e[6] = f2bf(b[2]); o.e[7] = f2bf(b[3]);
  *(bf16x8*)(dst + i * 8) = o.v;
}

// ---------------- shared 128x128 GEMM core (C = A * B^T), bf16, BK=32 -----
// DOUBLE-BUFFERED staging (round-5-verified k_attn pattern): prologue stages
// buf0; per iter {barrier -> prefetch next K-step into buf^1 -> compute buf}.
// One barrier/iter; HBM latency hides under the 16-MFMA compute phase.
// As/Bs are [2][4096] u16 (8KB per buffer, 32KB total LDS per block).
__device__ __forceinline__ void gemm_core(
    const u16* __restrict__ A, const u16* __restrict__ Bm,
    u16* As, u16* Bs, f32x4 acc[4][4], int m0, int n0) {
  const int t = threadIdx.x;
  const int lane = t & 63, w = t >> 6;
  const int wr = (w >> 1) * 64, wc = (w & 1) * 64;  // wave sub-tile 64x64
  const int lr = lane & 15, g = lane >> 4;
  const int rr = t >> 2, c8 = (t & 3) * 8;          // staging row/chunk
#pragma unroll
  for (int mi = 0; mi < 4; ++mi)
#pragma unroll
    for (int ni = 0; ni < 4; ++ni)
      acc[mi][ni] = (f32x4){0.f, 0.f, 0.f, 0.f};
  const u16* ga0 = A  + (size_t)(m0 + rr) * D_MODEL + c8;
  const u16* ga1 = A  + (size_t)(m0 + 64 + rr) * D_MODEL + c8;
  const u16* gb0 = Bm + (size_t)(n0 + rr) * D_MODEL + c8;
  const u16* gb1 = Bm + (size_t)(n0 + 64 + rr) * D_MODEL + c8;
  // prologue: stage K-step 0 into buffer 0
  async_copy16(ga0, As + t * 8);
  async_copy16(ga1, As + 2048 + t * 8);
  async_copy16(gb0, Bs + t * 8);
  async_copy16(gb1, Bs + 2048 + t * 8);
  int cur = 0;
  for (int k0 = 0; k0 < D_MODEL; k0 += 32) {
    __syncthreads();  // vmcnt+lgkm drain: buf[cur] ready, buf[cur^1] free
    if (k0 + 32 < D_MODEL) {  // prefetch next K-step into the other buffer
      u16* Ad = As + (cur ^ 1) * 4096;
      u16* Bd = Bs + (cur ^ 1) * 4096;
      async_copy16(ga0 + k0 + 32, Ad + t * 8);
      async_copy16(ga1 + k0 + 32, Ad + 2048 + t * 8);
      async_copy16(gb0 + k0 + 32, Bd + t * 8);
      async_copy16(gb1 + k0 + 32, Bd + 2048 + t * 8);
    }
    const u16* Ab = As + cur * 4096;
    const u16* Bb = Bs + cur * 4096;
    bf16x8 af[4], bfr[4];
#pragma unroll
    for (int mi = 0; mi < 4; ++mi)
      af[mi] = *(const bf16x8*)(Ab + (wr + mi * 16 + lr) * 32 + g * 8);
#pragma unroll
    for (int ni = 0; ni < 4; ++ni)
      bfr[ni] = *(const bf16x8*)(Bb + (wc + ni * 16 + lr) * 32 + g * 8);
#pragma unroll
    for (int mi = 0; mi < 4; ++mi)
#pragma unroll
      for (int ni = 0; ni < 4; ++ni)
        acc[mi][ni] = __builtin_amdgcn_mfma_f32_16x16x32_bf16(
            af[mi], bfr[ni], acc[mi][ni], 0, 0, 0);
    cur ^= 1;
  }
}

// ---------------- fused QKV projection ------------------------------------
// Q,K written [b,h,s,d]; V written TRANSPOSED Vt[b,h,d,s] for k_attn's
// b64 V-fragment reads. Q pre-scaled by QK_SCALE.
__global__ __launch_bounds__(256) void k_gemm_qkv(
    const u16* __restrict__ xb, const u16* __restrict__ wqb,
    const u16* __restrict__ wkb, const u16* __restrict__ wvb,
    u16* __restrict__ Qo, u16* __restrict__ Ko, u16* __restrict__ Vt) {
  __shared__ u16 As[2 * 4096], Bs[2 * 4096];
  const int m0 = blockIdx.x * 128;
  const int n0g = blockIdx.y * 128;
  const int proj = n0g >> 10;       // 0,1,2
  const int n0 = n0g & 1023;
  const u16* Bm = (proj == 0) ? wqb : (proj == 1) ? wkb : wvb;
  const float scale = (proj == 0) ? QK_SCALE : 1.0f;
  f32x4 acc[4][4];
  gemm_core(xb, Bm, As, Bs, acc, m0, n0);
  const int t = threadIdx.x, lane = t & 63, w = t >> 6;
  const int wr = (w >> 1) * 64, wc = (w & 1) * 64;
  const int lr = lane & 15, g = lane >> 4;
  if (proj != 2) {
    u16* Out = (proj == 0) ? Qo : Ko;
#pragma unroll
    for (int mi = 0; mi < 4; ++mi)
#pragma unroll
      for (int ni = 0; ni < 4; ++ni)
#pragma unroll
        for (int jj = 0; jj < 4; ++jj) {
          int m = m0 + wr + mi * 16 + 4 * g + jj;    // (b,s)
          int cn = n0 + wc + ni * 16 + lr;           // (h,d)
          int h = cn >> 6, d = cn & 63;
          int b = m >> 11, s = m & 2047;
          Out[(((size_t)(b * NH + h) * SEQ) + s) * DH + d] =
              f2bf(acc[mi][ni][jj] * scale);
        }
  } else {
    // Vt[((b*NH+h)*DH + d)*SEQ + s], 4 consecutive s packed per 8B store
#pragma unroll
    for (int mi = 0; mi < 4; ++mi)
#pragma unroll
      for (int ni = 0; ni < 4; ++ni) {
        u16x4 pk;
#pragma unroll
        for (int jj = 0; jj < 4; ++jj) pk[jj] = f2bf(acc[mi][ni][jj]);
        int mb = m0 + wr + mi * 16 + 4 * g;          // s = mb + jj (mb % 4 == 0)
        int cn = n0 + wc + ni * 16 + lr;
        int h = cn >> 6, d = cn & 63;
        int b = mb >> 11, s = mb & 2047;
        *(u16x4*)(Vt + (((size_t)(b * NH + h) * DH + d) * SEQ) + s) = pk;
      }
  }
}

// ---------------- flash attention (causal) --------------------------------
// 4 waves x 16 q-rows (QBLK=64), KVBLK=64, 4 blocks/CU. Swapped QK^T,
// in-register softmax; P->bf16 via cvt_pk; l via MFMA ones-column; defer-max
// THR=8. Double-buffered K/Vt staging. (round-11-verified, unchanged)
__global__ __launch_bounds__(256, 4) void k_attn(
    const u16* __restrict__ Q, const u16* __restrict__ K,
    const u16* __restrict__ Vt, u16* __restrict__ att) {
  __shared__ u16 Ksh[2][4096];
  __shared__ u16 Vsh[2][4096];
  const int t = threadIdx.x, lane = t & 63, w = t >> 6;
  const int lr = lane & 15, g = lane >> 4;
  // 4-class balanced, heavy-first: per-k4 nkv sums = 66
  const int bid = blockIdx.x;
  const int k4 = bid & 7;
  const int bh = (bid >> 3) & 31;
  const int j4 = bid >> 8;
  const int qb = (j4 == 0) ? (31 - k4) : (j4 == 1) ? k4
               : (j4 == 2) ? (23 - k4) : (8 + k4);
  const int q0 = qb * 64, qw = q0 + w * 16;
  const size_t hb = (size_t)bh * SEQ * DH;
  const u16* Qp  = Q  + hb;
  const u16* Kp  = K  + hb;
  const u16* Vtp = Vt + hb;   // [d][s] layout

  // Q B-fragments: lane holds Q[qw+lr][kk*32+8g..+7]
  bf16x8 qfr[2];
#pragma unroll
  for (int kk = 0; kk < 2; ++kk)
    qfr[kk] = *(const bf16x8*)(Qp + (size_t)(qw + lr) * DH + kk * 32 + g * 8);

  f32x4 o[4];
#pragma unroll
  for (int d = 0; d < 4; ++d) o[d] = (f32x4){0.f, 0.f, 0.f, 0.f};
  f32x4 lacc = (f32x4){0.f, 0.f, 0.f, 0.f};   // l for q=qw+4g+jj (same idx as o)
  float mrow = -__builtin_inff();

  // all-ones B fragment for the l-accumulation MFMA
  const short one_bf = (short)0x3F80;
  const bf16x8 onesb = {one_bf, one_bf, one_bf, one_bf,
                        one_bf, one_bf, one_bf, one_bf};

  // pre-swizzled per-thread staging sources (linear LDS dest t*16)
  const int sswz = ((t & 7) * 16) ^ (((t >> 3) & 7) << 4);
  const char* srcK = (const char*)Kp + (t >> 3) * 128 + sswz;
  const char* srcV = (const char*)Vtp + (t >> 3) * 4096 + sswz;

  const int nkv = qb + 1;
  int cur = 0;

  // prologue: stage tile 0 into buffer 0 (two 4KB halves each)
  async_copy16(srcK,          (char*)&Ksh[0][0] + t * 16);
  async_copy16(srcK + 4096,   (char*)&Ksh[0][0] + 4096 + t * 16);
  async_copy16(srcV,          (char*)&Vsh[0][0] + t * 16);
  async_copy16(srcV + 131072, (char*)&Vsh[0][0] + 4096 + t * 16);

  for (int it = 0; it < nkv; ++it) {
    const int kv0 = it * 64;
    __syncthreads();  // vmcnt drain -> buf[cur] ready
    if (it + 1 < nkv) {
      const char* sk = srcK + (size_t)(it + 1) * 8192;
      const char* sv = srcV + (size_t)(it + 1) * 128;
      char* kd = (char*)&Ksh[cur ^ 1][0];
      char* vd = (char*)&Vsh[cur ^ 1][0];
      async_copy16(sk,          kd + t * 16);
      async_copy16(sk + 4096,   kd + 4096 + t * 16);
      async_copy16(sv,          vd + t * 16);
      async_copy16(sv + 131072, vd + 4096 + t * 16);
    }
    if (kv0 <= qw + 15) {  // wave-uniform causal early-out
      const char* kbase = (const char*)&Ksh[cur][0];
      const char* vbase = (const char*)&Vsh[cur][0];
      // K A-fragments (swizzled b128 reads), kv rows mf*16+lr
      bf16x8 kfr[4][2];
#pragma unroll
      for (int mf = 0; mf < 4; ++mf) {
        int row = mf * 16 + lr;
#pragma unroll
        for (int kk = 0; kk < 2; ++kk) {
          int off = (row * 128 + kk * 64 + g * 16) ^ ((row & 7) << 4);
          kfr[mf][kk] = *(const bf16x8*)(kbase + off);
        }
      }
      // S^T = K Q^T : rows kv (mf 0..3), col q = lr
      f32x4 st[4];
#pragma unroll
      for (int mf = 0; mf < 4; ++mf) {
        f32x4 z = (f32x4){0.f, 0.f, 0.f, 0.f};
        z = __builtin_amdgcn_mfma_f32_16x16x32_bf16(kfr[mf][0], qfr[0], z, 0, 0, 0);
        st[mf] = __builtin_amdgcn_mfma_f32_16x16x32_bf16(kfr[mf][1], qfr[1], z, 0, 0, 0);
      }
      if (kv0 + 63 > qw) {  // diagonal block: per-element causal mask
#pragma unroll
        for (int mf = 0; mf < 4; ++mf)
#pragma unroll
          for (int jj = 0; jj < 4; ++jj) {
            int kv = kv0 + mf * 16 + 4 * g + jj;
            st[mf][jj] = (kv > qw + lr) ? -__builtin_inff() : st[mf][jj];
          }
      }
      // tile max over kv for q = lr
      float v01 = fmaxf(fmaxf(fmaxf(st[0][0], st[0][1]), fmaxf(st[0][2], st[0][3])),
                        fmaxf(fmaxf(st[1][0], st[1][1]), fmaxf(st[1][2], st[1][3])));
      float v23 = fmaxf(fmaxf(fmaxf(st[2][0], st[2][1]), fmaxf(st[2][2], st[2][3])),
                        fmaxf(fmaxf(st[3][0], st[3][1]), fmaxf(st[3][2], st[3][3])));
      float v = fmaxf(v01, v23);
      v = fmaxf(v, __shfl_xor(v, 16));
      v = fmaxf(v, __shfl_xor(v, 32));
      // defer-max (T13): rescale only if max grew by > 8 (exp2 domain)
      if (__any(v > mrow + 8.0f)) {
        float mnew = fmaxf(mrow, v);
        float fac = exp2f(mrow - mnew);
        mrow = mnew;
        float fq[4];
#pragma unroll
        for (int jj = 0; jj < 4; ++jj)
          fq[jj] = __shfl(fac, 4 * g + jj);
#pragma unroll
        for (int d = 0; d < 4; ++d)
#pragma unroll
          for (int jj = 0; jj < 4; ++jj)
            o[d][jj] *= fq[jj];
#pragma unroll
        for (int jj = 0; jj < 4; ++jj)
          lacc[jj] *= fq[jj];
      }
      // P = exp2(S - m); bounded by 2^8 when deferred
      float p[4][4];
#pragma unroll
      for (int mf = 0; mf < 4; ++mf)
#pragma unroll
        for (int jj = 0; jj < 4; ++jj)
          p[mf][jj] = exp2f(st[mf][jj] - mrow);
      // P -> bf16 A-fragments via cvt_pk; slot m4*4+jj <- p[ks*2+m4][jj]
      bf16x8 pa[2];
#pragma unroll
      for (int ks = 0; ks < 2; ++ks) {
        union { bf16x8 v8; u32 wdz[4]; } pu;
        pu.wdz[0] = cvtpk(p[ks * 2][0],     p[ks * 2][1]);
        pu.wdz[1] = cvtpk(p[ks * 2][2],     p[ks * 2][3]);
        pu.wdz[2] = cvtpk(p[ks * 2 + 1][0], p[ks * 2 + 1][1]);
        pu.wdz[3] = cvtpk(p[ks * 2 + 1][2], p[ks * 2 + 1][3]);
        pa[ks] = pu.v8;
      }
      // l accumulation on the MFMA pipe: C[q][*] = sum_kv P (B = ones)
      lacc = __builtin_amdgcn_mfma_f32_16x16x32_bf16(pa[0], onesb, lacc, 0, 0, 0);
      lacc = __builtin_amdgcn_mfma_f32_16x16x32_bf16(pa[1], onesb, lacc, 0, 0, 0);
      // V B-fragments from Vt LDS: b64 reads, jj-contiguous
#pragma unroll
      for (int ks = 0; ks < 2; ++ks) {
        bf16x8 vb[4];
#pragma unroll
        for (int dd = 0; dd < 4; ++dd) {
          int row = dd * 16 + lr;
          int sz = (row & 7) << 4;
          union { bf16x8 v8; bf16x4 h[2]; } u;
          u.h[0] = *(const bf16x4*)(vbase + ((row * 128 + ks * 64 + g * 8) ^ sz));
          u.h[1] = *(const bf16x4*)(vbase + ((row * 128 + ks * 64 + 32 + g * 8) ^ sz));
          vb[dd] = u.v8;
        }
#pragma unroll
        for (int dd = 0; dd < 4; ++dd)
          o[dd] = __builtin_amdgcn_mfma_f32_16x16x32_bf16(pa[ks], vb[dd], o[dd], 0, 0, 0);
      }
    }
    cur ^= 1;
  }
  // epilogue: divide by l (lane-local), write att[b, q, h*64+d] bf16
  const int b = bh >> 4, h = bh & 15;
#pragma unroll
  for (int jj = 0; jj < 4; ++jj) {
    float li = 1.0f / lacc[jj];
    int q = qw + 4 * g + jj;
#pragma unroll
    for (int d = 0; d < 4; ++d) {
      int cn = h * 64 + d * 16 + lr;
      att[(size_t)(b * SEQ + q) * D_MODEL + cn] = f2bf(o[d][jj] * li);
    }
  }
}

// ---------------- output projection (fp32 out) ----------------------------
__global__ __launch_bounds__(256) void k_gemm_out(
    const u16* __restrict__ att, const u16* __restrict__ wob,
    float* __restrict__ out) {
  __shared__ u16 As[2 * 4096], Bs[2 * 4096];
  const int m0 = blockIdx.x * 128, n0 = blockIdx.y * 128;
  f32x4 acc[4][4];
  gemm_core(att, wob, As, Bs, acc, m0, n0);
  const int t = threadIdx.x, lane = t & 63, w = t >> 6;
  const int wr = (w >> 1) * 64, wc = (w & 1) * 64;
  const int lr = lane & 15, g = lane >> 4;
#pragma unroll
  for (int mi = 0; mi < 4; ++mi)
#pragma unroll
    for (int ni = 0; ni < 4; ++ni)
#pragma unroll
      for (int jj = 0; jj < 4; ++jj) {
        int m = m0 + wr + mi * 16 + 4 * g + jj;
        int n = n0 + wc + ni * 16 + lr;
        out[(size_t)m * D_MODEL + n] = acc[mi][ni][jj];
      }
}

extern "C" void kernel_launch(void* const* d_in, const int* in_sizes, int n_in,
                              void* d_out, int out_size, void* d_ws, size_t ws_size,
                              hipStream_t stream) {
  (void)in_sizes; (void)n_in; (void)out_size; (void)ws_size;
  const float* x  = (const float*)d_in[0];
  const float* WQ = (const float*)d_in[1];
  const float* WK = (const float*)d_in[2];
  const float* WV = (const float*)d_in[3];
  const float* WO = (const float*)d_in[4];
  float* out = (float*)d_out;
  char* ws = (char*)d_ws;
  u16* xb  = (u16*)(ws);
  u16* wqb = (u16*)(ws + ((size_t)8 << 20));
  u16* wkb = (u16*)(ws + ((size_t)10 << 20));
  u16* wvb = (u16*)(ws + ((size_t)12 << 20));
  u16* wob = (u16*)(ws + ((size_t)14 << 20));
  u16* Qb  = (u16*)(ws + ((size_t)16 << 20));
  u16* Kb  = (u16*)(ws + ((size_t)24 << 20));
  u16* Vtb = (u16*)(ws + ((size_t)32 << 20));
  u16* att = (u16*)(ws + ((size_t)40 << 20));

  hipLaunchKernelGGL(k_convert, dim3(4096), dim3(256), 0, stream,
                     x, WQ, WK, WV, WO, xb, wqb, wkb, wvb, wob);
  hipLaunchKernelGGL(k_gemm_qkv, dim3(32, 24), dim3(256), 0, stream,
                     xb, wqb, wkb, wvb, Qb, Kb, Vtb);
  hipLaunchKernelGGL(k_attn, dim3(1024), dim3(256), 0, stream,
                     Qb, Kb, Vtb, att);
  hipLaunchKernelGGL(k_gemm_out, dim3(32, 8), dim3(256), 0, stream,
                     att, wob, out);
}

// Round 14
// 177.186 us; speedup vs baseline: 1.4668x; 1.0267x over previous
//
#include <hip/hip_runtime.h>
#include <hip/hip_bf16.h>
#include <math.h>

typedef unsigned int u32;
typedef unsigned short u16;
typedef __attribute__((ext_vector_type(4))) float f32x4;
typedef __attribute__((ext_vector_type(4))) short bf16x4;
typedef __attribute__((ext_vector_type(8))) short bf16x8;
typedef __attribute__((ext_vector_type(4))) unsigned short u16x4;

#define D_MODEL 1024
#define SEQ     2048
#define NH      16
#define DH      64
#define MTOT    4096

// 1/sqrt(64) * log2(e): folded into Q so softmax uses exp2
#define QK_SCALE (0.125f * 1.44269504088896340736f)

__device__ __forceinline__ u16 f2bf(float f) {
  union { float f; u32 u; } a; a.f = f;
  u32 r = a.u + 0x7fffu + ((a.u >> 16) & 1u);  // RNE
  return (u16)(r >> 16);
}

// packed f32->bf16 RNE convert (T12 primitive)
__device__ __forceinline__ u32 cvtpk(float lo, float hi) {
  u32 r;
  asm("v_cvt_pk_bf16_f32 %0, %1, %2" : "=v"(r) : "v"(lo), "v"(hi));
  return r;
}

// raw HW exp2 (v_exp_f32): 1 instr vs ~6 for libm exp2f; domain here is
// [-inf, 8], exp(-inf)=0 exact. CDNA VALU deps are HW-interlocked.
__device__ __forceinline__ float exp2_hw(float x) {
  float r;
  asm("v_exp_f32 %0, %1" : "=v"(r) : "v"(x));
  return r;
}

// max3-fusable triple (clang fuses nested fmaxf into v_max3_f32)
__device__ __forceinline__ float fmax3(float a, float b, float c) {
  return fmaxf(fmaxf(a, b), c);
}

__device__ __forceinline__ void async_copy16(const void* g, void* l) {
  __builtin_amdgcn_global_load_lds(
      (const __attribute__((address_space(1))) u32*)g,
      (__attribute__((address_space(3))) u32*)l, 16, 0, 0);
}

// ---------------- fp32 -> bf16 conversion of x and weights ----------------
__global__ __launch_bounds__(256) void k_convert(
    const float* __restrict__ x,  const float* __restrict__ wq,
    const float* __restrict__ wk, const float* __restrict__ wv,
    const float* __restrict__ wo,
    u16* __restrict__ xb,  u16* __restrict__ wqb, u16* __restrict__ wkb,
    u16* __restrict__ wvb, u16* __restrict__ wob) {
  const long NX = (long)MTOT * D_MODEL / 8;     // 524288 groups of 8
  const long NW = (long)D_MODEL * D_MODEL / 8;  // 131072
  long i = (long)blockIdx.x * 256 + threadIdx.x;
  const float* src; u16* dst;
  if (i < NX)               { src = x;  dst = xb;  }
  else if (i < NX + NW)     { src = wq; dst = wqb; i -= NX; }
  else if (i < NX + 2*NW)   { src = wk; dst = wkb; i -= NX + 2*NW - NW; }
  else if (i < NX + 3*NW)   { src = wv; dst = wvb; i -= NX + 2*NW; }
  else                      { src = wo; dst = wob; i -= NX + 3*NW; }
  const f32x4* s4 = (const f32x4*)src + i * 2;
  f32x4 a = s4[0], b = s4[1];
  union { bf16x8 v; u16 e[8]; } o;
  o.e[0] = f2bf(a[0]); o.e[1] = f2bf(a[1]); o.e[2] = f2bf(a[2]); o.e[3] = f2bf(a[3]);
  o.e[4] = f2bf(b[0]); o.e[5] = f2bf(b[1]); o.e[6] = f2bf(b[2]); o.e[7] = f2bf(b[3]);
  *(bf16x8*)(dst + i * 8) = o.v;
}

// ---------------- shared 128x128 GEMM core (C = A * B^T), bf16, BK=32 -----
// DOUBLE-BUFFERED staging (verified round 13).
__device__ __forceinline__ void gemm_core(
    const u16* __restrict__ A, const u16* __restrict__ Bm,
    u16* As, u16* Bs, f32x4 acc[4][4], int m0, int n0) {
  const int t = threadIdx.x;
  const int lane = t & 63, w = t >> 6;
  const int wr = (w >> 1) * 64, wc = (w & 1) * 64;  // wave sub-tile 64x64
  const int lr = lane & 15, g = lane >> 4;
  const int rr = t >> 2, c8 = (t & 3) * 8;          // staging row/chunk
#pragma unroll
  for (int mi = 0; mi < 4; ++mi)
#pragma unroll
    for (int ni = 0; ni < 4; ++ni)
      acc[mi][ni] = (f32x4){0.f, 0.f, 0.f, 0.f};
  const u16* ga0 = A  + (size_t)(m0 + rr) * D_MODEL + c8;
  const u16* ga1 = A  + (size_t)(m0 + 64 + rr) * D_MODEL + c8;
  const u16* gb0 = Bm + (size_t)(n0 + rr) * D_MODEL + c8;
  const u16* gb1 = Bm + (size_t)(n0 + 64 + rr) * D_MODEL + c8;
  // prologue: stage K-step 0 into buffer 0
  async_copy16(ga0, As + t * 8);
  async_copy16(ga1, As + 2048 + t * 8);
  async_copy16(gb0, Bs + t * 8);
  async_copy16(gb1, Bs + 2048 + t * 8);
  int cur = 0;
  for (int k0 = 0; k0 < D_MODEL; k0 += 32) {
    __syncthreads();  // vmcnt+lgkm drain: buf[cur] ready, buf[cur^1] free
    if (k0 + 32 < D_MODEL) {  // prefetch next K-step into the other buffer
      u16* Ad = As + (cur ^ 1) * 4096;
      u16* Bd = Bs + (cur ^ 1) * 4096;
      async_copy16(ga0 + k0 + 32, Ad + t * 8);
      async_copy16(ga1 + k0 + 32, Ad + 2048 + t * 8);
      async_copy16(gb0 + k0 + 32, Bd + t * 8);
      async_copy16(gb1 + k0 + 32, Bd + 2048 + t * 8);
    }
    const u16* Ab = As + cur * 4096;
    const u16* Bb = Bs + cur * 4096;
    bf16x8 af[4], bfr[4];
#pragma unroll
    for (int mi = 0; mi < 4; ++mi)
      af[mi] = *(const bf16x8*)(Ab + (wr + mi * 16 + lr) * 32 + g * 8);
#pragma unroll
    for (int ni = 0; ni < 4; ++ni)
      bfr[ni] = *(const bf16x8*)(Bb + (wc + ni * 16 + lr) * 32 + g * 8);
#pragma unroll
    for (int mi = 0; mi < 4; ++mi)
#pragma unroll
      for (int ni = 0; ni < 4; ++ni)
        acc[mi][ni] = __builtin_amdgcn_mfma_f32_16x16x32_bf16(
            af[mi], bfr[ni], acc[mi][ni], 0, 0, 0);
    cur ^= 1;
  }
}

// ---------------- fused QKV projection ------------------------------------
// Q,K written [b,h,s,d]; V written TRANSPOSED Vt[b,h,d,s] for k_attn's
// b64 V-fragment reads. Q pre-scaled by QK_SCALE.
__global__ __launch_bounds__(256) void k_gemm_qkv(
    const u16* __restrict__ xb, const u16* __restrict__ wqb,
    const u16* __restrict__ wkb, const u16* __restrict__ wvb,
    u16* __restrict__ Qo, u16* __restrict__ Ko, u16* __restrict__ Vt) {
  __shared__ u16 As[2 * 4096], Bs[2 * 4096];
  const int m0 = blockIdx.x * 128;
  const int n0g = blockIdx.y * 128;
  const int proj = n0g >> 10;       // 0,1,2
  const int n0 = n0g & 1023;
  const u16* Bm = (proj == 0) ? wqb : (proj == 1) ? wkb : wvb;
  const float scale = (proj == 0) ? QK_SCALE : 1.0f;
  f32x4 acc[4][4];
  gemm_core(xb, Bm, As, Bs, acc, m0, n0);
  const int t = threadIdx.x, lane = t & 63, w = t >> 6;
  const int wr = (w >> 1) * 64, wc = (w & 1) * 64;
  const int lr = lane & 15, g = lane >> 4;
  if (proj != 2) {
    u16* Out = (proj == 0) ? Qo : Ko;
#pragma unroll
    for (int mi = 0; mi < 4; ++mi)
#pragma unroll
      for (int ni = 0; ni < 4; ++ni)
#pragma unroll
        for (int jj = 0; jj < 4; ++jj) {
          int m = m0 + wr + mi * 16 + 4 * g + jj;    // (b,s)
          int cn = n0 + wc + ni * 16 + lr;           // (h,d)
          int h = cn >> 6, d = cn & 63;
          int b = m >> 11, s = m & 2047;
          Out[(((size_t)(b * NH + h) * SEQ) + s) * DH + d] =
              f2bf(acc[mi][ni][jj] * scale);
        }
  } else {
    // Vt[((b*NH+h)*DH + d)*SEQ + s], 4 consecutive s packed per 8B store
#pragma unroll
    for (int mi = 0; mi < 4; ++mi)
#pragma unroll
      for (int ni = 0; ni < 4; ++ni) {
        u16x4 pk;
#pragma unroll
        for (int jj = 0; jj < 4; ++jj) pk[jj] = f2bf(acc[mi][ni][jj]);
        int mb = m0 + wr + mi * 16 + 4 * g;          // s = mb + jj (mb % 4 == 0)
        int cn = n0 + wc + ni * 16 + lr;
        int h = cn >> 6, d = cn & 63;
        int b = mb >> 11, s = mb & 2047;
        *(u16x4*)(Vt + (((size_t)(b * NH + h) * DH + d) * SEQ) + s) = pk;
      }
  }
}

// ---------------- flash attention (causal) --------------------------------
// Round-11-verified structure; this round: raw v_exp_f32 (replaces libm
// exp2f ~6-instr expansion) + max3-structured tile-max reduction.
__global__ __launch_bounds__(256, 4) void k_attn(
    const u16* __restrict__ Q, const u16* __restrict__ K,
    const u16* __restrict__ Vt, u16* __restrict__ att) {
  __shared__ u16 Ksh[2][4096];
  __shared__ u16 Vsh[2][4096];
  const int t = threadIdx.x, lane = t & 63, w = t >> 6;
  const int lr = lane & 15, g = lane >> 4;
  // 4-class balanced, heavy-first: per-k4 nkv sums = 66
  const int bid = blockIdx.x;
  const int k4 = bid & 7;
  const int bh = (bid >> 3) & 31;
  const int j4 = bid >> 8;
  const int qb = (j4 == 0) ? (31 - k4) : (j4 == 1) ? k4
               : (j4 == 2) ? (23 - k4) : (8 + k4);
  const int q0 = qb * 64, qw = q0 + w * 16;
  const size_t hb = (size_t)bh * SEQ * DH;
  const u16* Qp  = Q  + hb;
  const u16* Kp  = K  + hb;
  const u16* Vtp = Vt + hb;   // [d][s] layout

  // Q B-fragments: lane holds Q[qw+lr][kk*32+8g..+7]
  bf16x8 qfr[2];
#pragma unroll
  for (int kk = 0; kk < 2; ++kk)
    qfr[kk] = *(const bf16x8*)(Qp + (size_t)(qw + lr) * DH + kk * 32 + g * 8);

  f32x4 o[4];
#pragma unroll
  for (int d = 0; d < 4; ++d) o[d] = (f32x4){0.f, 0.f, 0.f, 0.f};
  f32x4 lacc = (f32x4){0.f, 0.f, 0.f, 0.f};   // l for q=qw+4g+jj (same idx as o)
  float mrow = -__builtin_inff();

  // all-ones B fragment for the l-accumulation MFMA
  const short one_bf = (short)0x3F80;
  const bf16x8 onesb = {one_bf, one_bf, one_bf, one_bf,
                        one_bf, one_bf, one_bf, one_bf};

  // pre-swizzled per-thread staging sources (linear LDS dest t*16)
  const int sswz = ((t & 7) * 16) ^ (((t >> 3) & 7) << 4);
  const char* srcK = (const char*)Kp + (t >> 3) * 128 + sswz;
  const char* srcV = (const char*)Vtp + (t >> 3) * 4096 + sswz;

  const int nkv = qb + 1;
  int cur = 0;

  // prologue: stage tile 0 into buffer 0 (two 4KB halves each)
  async_copy16(srcK,          (char*)&Ksh[0][0] + t * 16);
  async_copy16(srcK + 4096,   (char*)&Ksh[0][0] + 4096 + t * 16);
  async_copy16(srcV,          (char*)&Vsh[0][0] + t * 16);
  async_copy16(srcV + 131072, (char*)&Vsh[0][0] + 4096 + t * 16);

  for (int it = 0; it < nkv; ++it) {
    const int kv0 = it * 64;
    __syncthreads();  // vmcnt drain -> buf[cur] ready
    if (it + 1 < nkv) {
      const char* sk = srcK + (size_t)(it + 1) * 8192;
      const char* sv = srcV + (size_t)(it + 1) * 128;
      char* kd = (char*)&Ksh[cur ^ 1][0];
      char* vd = (char*)&Vsh[cur ^ 1][0];
      async_copy16(sk,          kd + t * 16);
      async_copy16(sk + 4096,   kd + 4096 + t * 16);
      async_copy16(sv,          vd + t * 16);
      async_copy16(sv + 131072, vd + 4096 + t * 16);
    }
    if (kv0 <= qw + 15) {  // wave-uniform causal early-out
      const char* kbase = (const char*)&Ksh[cur][0];
      const char* vbase = (const char*)&Vsh[cur][0];
      // K A-fragments (swizzled b128 reads), kv rows mf*16+lr
      bf16x8 kfr[4][2];
#pragma unroll
      for (int mf = 0; mf < 4; ++mf) {
        int row = mf * 16 + lr;
#pragma unroll
        for (int kk = 0; kk < 2; ++kk) {
          int off = (row * 128 + kk * 64 + g * 16) ^ ((row & 7) << 4);
          kfr[mf][kk] = *(const bf16x8*)(kbase + off);
        }
      }
      // S^T = K Q^T : rows kv (mf 0..3), col q = lr
      f32x4 st[4];
#pragma unroll
      for (int mf = 0; mf < 4; ++mf) {
        f32x4 z = (f32x4){0.f, 0.f, 0.f, 0.f};
        z = __builtin_amdgcn_mfma_f32_16x16x32_bf16(kfr[mf][0], qfr[0], z, 0, 0, 0);
        st[mf] = __builtin_amdgcn_mfma_f32_16x16x32_bf16(kfr[mf][1], qfr[1], z, 0, 0, 0);
      }
      if (kv0 + 63 > qw) {  // diagonal block: per-element causal mask
#pragma unroll
        for (int mf = 0; mf < 4; ++mf)
#pragma unroll
          for (int jj = 0; jj < 4; ++jj) {
            int kv = kv0 + mf * 16 + 4 * g + jj;
            st[mf][jj] = (kv > qw + lr) ? -__builtin_inff() : st[mf][jj];
          }
      }
      // tile max over kv for q = lr (max3-structured: 8 ops vs 15)
      float r1 = fmax3(st[0][0], st[0][1], st[0][2]);
      float r2 = fmax3(st[0][3], st[1][0], st[1][1]);
      float r3 = fmax3(st[1][2], st[1][3], st[2][0]);
      float r4 = fmax3(st[2][1], st[2][2], st[2][3]);
      float r5 = fmax3(st[3][0], st[3][1], st[3][2]);
      float v = fmax3(fmax3(r1, r2, r3), fmax3(r4, r5, st[3][3]),
                      -__builtin_inff());
      v = fmaxf(v, __shfl_xor(v, 16));
      v = fmaxf(v, __shfl_xor(v, 32));
      // defer-max (T13): rescale only if max grew by > 8 (exp2 domain)
      if (__any(v > mrow + 8.0f)) {
        float mnew = fmaxf(mrow, v);
        float fac = exp2_hw(mrow - mnew);
        mrow = mnew;
        float fq[4];
#pragma unroll
        for (int jj = 0; jj < 4; ++jj)
          fq[jj] = __shfl(fac, 4 * g + jj);
#pragma unroll
        for (int d = 0; d < 4; ++d)
#pragma unroll
          for (int jj = 0; jj < 4; ++jj)
            o[d][jj] *= fq[jj];
#pragma unroll
        for (int jj = 0; jj < 4; ++jj)
          lacc[jj] *= fq[jj];
      }
      // P = exp2(S - m) via raw v_exp_f32; bounded by 2^8 when deferred
      float p[4][4];
#pragma unroll
      for (int mf = 0; mf < 4; ++mf)
#pragma unroll
        for (int jj = 0; jj < 4; ++jj)
          p[mf][jj] = exp2_hw(st[mf][jj] - mrow);
      // P -> bf16 A-fragments via cvt_pk; slot m4*4+jj <- p[ks*2+m4][jj]
      bf16x8 pa[2];
#pragma unroll
      for (int ks = 0; ks < 2; ++ks) {
        union { bf16x8 v8; u32 wdz[4]; } pu;
        pu.wdz[0] = cvtpk(p[ks * 2][0],     p[ks * 2][1]);
        pu.wdz[1] = cvtpk(p[ks * 2][2],     p[ks * 2][3]);
        pu.wdz[2] = cvtpk(p[ks * 2 + 1][0], p[ks * 2 + 1][1]);
        pu.wdz[3] = cvtpk(p[ks * 2 + 1][2], p[ks * 2 + 1][3]);
        pa[ks] = pu.v8;
      }
      // l accumulation on the MFMA pipe: C[q][*] = sum_kv P (B = ones)
      lacc = __builtin_amdgcn_mfma_f32_16x16x32_bf16(pa[0], onesb, lacc, 0, 0, 0);
      lacc = __builtin_amdgcn_mfma_f32_16x16x32_bf16(pa[1], onesb, lacc, 0, 0, 0);
      // V B-fragments from Vt LDS: b64 reads, jj-contiguous
#pragma unroll
      for (int ks = 0; ks < 2; ++ks) {
        bf16x8 vb[4];
#pragma unroll
        for (int dd = 0; dd < 4; ++dd) {
          int row = dd * 16 + lr;
          int sz = (row & 7) << 4;
          union { bf16x8 v8; bf16x4 h[2]; } u;
          u.h[0] = *(const bf16x4*)(vbase + ((row * 128 + ks * 64 + g * 8) ^ sz));
          u.h[1] = *(const bf16x4*)(vbase + ((row * 128 + ks * 64 + 32 + g * 8) ^ sz));
          vb[dd] = u.v8;
        }
#pragma unroll
        for (int dd = 0; dd < 4; ++dd)
          o[dd] = __builtin_amdgcn_mfma_f32_16x16x32_bf16(pa[ks], vb[dd], o[dd], 0, 0, 0);
      }
    }
    cur ^= 1;
  }
  // epilogue: divide by l (lane-local), write att[b, q, h*64+d] bf16
  const int b = bh >> 4, h = bh & 15;
#pragma unroll
  for (int jj = 0; jj < 4; ++jj) {
    float li = 1.0f / lacc[jj];
    int q = qw + 4 * g + jj;
#pragma unroll
    for (int d = 0; d < 4; ++d) {
      int cn = h * 64 + d * 16 + lr;
      att[(size_t)(b * SEQ + q) * D_MODEL + cn] = f2bf(o[d][jj] * li);
    }
  }
}

// ---------------- output projection (fp32 out) ----------------------------
// 64x64 tiles -> grid (64,16) = 1024 blocks = 4/CU (was 1/CU at 128x128):
// trades MFMA:overhead ratio for 4x occupancy on this latency-bound kernel.
// Same verified dbuf staging pattern; LDS 16KB/block.
__global__ __launch_bounds__(256, 4) void k_gemm_out(
    const u16* __restrict__ att, const u16* __restrict__ wob,
    float* __restrict__ out) {
  __shared__ u16 As[2 * 2048], Bs[2 * 2048];
  const int m0 = blockIdx.x * 64, n0 = blockIdx.y * 64;
  const int t = threadIdx.x, lane = t & 63, w = t >> 6;
  const int wr = (w >> 1) * 32, wc = (w & 1) * 32;  // wave sub-tile 32x32
  const int lr = lane & 15, g = lane >> 4;
  const int rr = t >> 2, c8 = (t & 3) * 8;
  f32x4 acc[2][2];
#pragma unroll
  for (int mi = 0; mi < 2; ++mi)
#pragma unroll
    for (int ni = 0; ni < 2; ++ni)
      acc[mi][ni] = (f32x4){0.f, 0.f, 0.f, 0.f};
  const u16* ga0 = att + (size_t)(m0 + rr) * D_MODEL + c8;
  const u16* gb0 = wob + (size_t)(n0 + rr) * D_MODEL + c8;
  // prologue: stage K-step 0 into buffer 0 (one copy16/thread per matrix)
  async_copy16(ga0, As + t * 8);
  async_copy16(gb0, Bs + t * 8);
  int cur = 0;
  for (int k0 = 0; k0 < D_MODEL; k0 += 32) {
    __syncthreads();
    if (k0 + 32 < D_MODEL) {
      async_copy16(ga0 + k0 + 32, As + (cur ^ 1) * 2048 + t * 8);
      async_copy16(gb0 + k0 + 32, Bs + (cur ^ 1) * 2048 + t * 8);
    }
    const u16* Ab = As + cur * 2048;
    const u16* Bb = Bs + cur * 2048;
    bf16x8 af[2], bfr[2];
#pragma unroll
    for (int mi = 0; mi < 2; ++mi)
      af[mi] = *(const bf16x8*)(Ab + (wr + mi * 16 + lr) * 32 + g * 8);
#pragma unroll
    for (int ni = 0; ni < 2; ++ni)
      bfr[ni] = *(const bf16x8*)(Bb + (wc + ni * 16 + lr) * 32 + g * 8);
#pragma unroll
    for (int mi = 0; mi < 2; ++mi)
#pragma unroll
      for (int ni = 0; ni < 2; ++ni)
        acc[mi][ni] = __builtin_amdgcn_mfma_f32_16x16x32_bf16(
            af[mi], bfr[ni], acc[mi][ni], 0, 0, 0);
    cur ^= 1;
  }
#pragma unroll
  for (int mi = 0; mi < 2; ++mi)
#pragma unroll
    for (int ni = 0; ni < 2; ++ni)
#pragma unroll
      for (int jj = 0; jj < 4; ++jj) {
        int m = m0 + wr + mi * 16 + 4 * g + jj;
        int n = n0 + wc + ni * 16 + lr;
        out[(size_t)m * D_MODEL + n] = acc[mi][ni][jj];
      }
}

extern "C" void kernel_launch(void* const* d_in, const int* in_sizes, int n_in,
                              void* d_out, int out_size, void* d_ws, size_t ws_size,
                              hipStream_t stream) {
  (void)in_sizes; (void)n_in; (void)out_size; (void)ws_size;
  const float* x  = (const float*)d_in[0];
  const float* WQ = (const float*)d_in[1];
  const float* WK = (const float*)d_in[2];
  const float* WV = (const float*)d_in[3];
  const float* WO = (const float*)d_in[4];
  float* out = (float*)d_out;
  char* ws = (char*)d_ws;
  u16* xb  = (u16*)(ws);
  u16* wqb = (u16*)(ws + ((size_t)8 << 20));
  u16* wkb = (u16*)(ws + ((size_t)10 << 20));
  u16* wvb = (u16*)(ws + ((size_t)12 << 20));
  u16* wob = (u16*)(ws + ((size_t)14 << 20));
  u16* Qb  = (u16*)(ws + ((size_t)16 << 20));
  u16* Kb  = (u16*)(ws + ((size_t)24 << 20));
  u16* Vtb = (u16*)(ws + ((size_t)32 << 20));
  u16* att = (u16*)(ws + ((size_t)40 << 20));

  hipLaunchKernelGGL(k_convert, dim3(4096), dim3(256), 0, stream,
                     x, WQ, WK, WV, WO, xb, wqb, wkb, wvb, wob);
  hipLaunchKernelGGL(k_gemm_qkv, dim3(32, 24), dim3(256), 0, stream,
                     xb, wqb, wkb, wvb, Qb, Kb, Vtb);
  hipLaunchKernelGGL(k_attn, dim3(1024), dim3(256), 0, stream,
                     Qb, Kb, Vtb, att);
  hipLaunchKernelGGL(k_gemm_out, dim3(64, 16), dim3(256), 0, stream,
                     att, wob, out);
}

// Round 15
// 175.968 us; speedup vs baseline: 1.4770x; 1.0069x over previous
//
#include <hip/hip_runtime.h>
#include <hip/hip_bf16.h>
#include <math.h>

typedef unsigned int u32;
typedef unsigned short u16;
typedef __attribute__((ext_vector_type(4))) float f32x4;
typedef __attribute__((ext_vector_type(4))) short bf16x4;
typedef __attribute__((ext_vector_type(8))) short bf16x8;
typedef __attribute__((ext_vector_type(4))) unsigned short u16x4;

#define D_MODEL 1024
#define SEQ     2048
#define NH      16
#define DH      64
#define MTOT    4096

// 1/sqrt(64) * log2(e): folded into Q so softmax uses exp2
#define QK_SCALE (0.125f * 1.44269504088896340736f)

__device__ __forceinline__ u16 f2bf(float f) {
  union { float f; u32 u; } a; a.f = f;
  u32 r = a.u + 0x7fffu + ((a.u >> 16) & 1u);  // RNE
  return (u16)(r >> 16);
}

// packed f32->bf16 RNE convert (T12 primitive)
__device__ __forceinline__ u32 cvtpk(float lo, float hi) {
  u32 r;
  asm("v_cvt_pk_bf16_f32 %0, %1, %2" : "=v"(r) : "v"(lo), "v"(hi));
  return r;
}

// raw HW exp2 (v_exp_f32): 1 instr vs ~6 for libm exp2f; domain [-inf, 8].
__device__ __forceinline__ float exp2_hw(float x) {
  float r;
  asm("v_exp_f32 %0, %1" : "=v"(r) : "v"(x));
  return r;
}

// max3-fusable triple (clang fuses nested fmaxf into v_max3_f32)
__device__ __forceinline__ float fmax3(float a, float b, float c) {
  return fmaxf(fmaxf(a, b), c);
}

__device__ __forceinline__ void async_copy16(const void* g, void* l) {
  __builtin_amdgcn_global_load_lds(
      (const __attribute__((address_space(1))) u32*)g,
      (__attribute__((address_space(3))) u32*)l, 16, 0, 0);
}

// ---------------- fp32 -> bf16 conversion of x and weights ----------------
__global__ __launch_bounds__(256) void k_convert(
    const float* __restrict__ x,  const float* __restrict__ wq,
    const float* __restrict__ wk, const float* __restrict__ wv,
    const float* __restrict__ wo,
    u16* __restrict__ xb,  u16* __restrict__ wqb, u16* __restrict__ wkb,
    u16* __restrict__ wvb, u16* __restrict__ wob) {
  const long NX = (long)MTOT * D_MODEL / 8;     // 524288 groups of 8
  const long NW = (long)D_MODEL * D_MODEL / 8;  // 131072
  long i = (long)blockIdx.x * 256 + threadIdx.x;
  const float* src; u16* dst;
  if (i < NX)               { src = x;  dst = xb;  }
  else if (i < NX + NW)     { src = wq; dst = wqb; i -= NX; }
  else if (i < NX + 2*NW)   { src = wk; dst = wkb; i -= NX + 2*NW - NW; }
  else if (i < NX + 3*NW)   { src = wv; dst = wvb; i -= NX + 2*NW; }
  else                      { src = wo; dst = wob; i -= NX + 3*NW; }
  const f32x4* s4 = (const f32x4*)src + i * 2;
  f32x4 a = s4[0], b = s4[1];
  union { bf16x8 v; u16 e[8]; } o;
  o.e[0] = f2bf(a[0]); o.e[1] = f2bf(a[1]); o.e[2] = f2bf(a[2]); o.e[3] = f2bf(a[3]);
  o.e[4] = f2bf(b[0]); o.e[5] = f2bf(b[1]); o.e[6] = f2bf(b[2]); o.e[7] = f2bf(b[3]);
  *(bf16x8*)(dst + i * 8) = o.v;
}

// ---------------- shared 128x128 GEMM core (C = A * B^T), bf16, BK=32 -----
// DOUBLE-BUFFERED staging (verified round 13).
__device__ __forceinline__ void gemm_core(
    const u16* __restrict__ A, const u16* __restrict__ Bm,
    u16* As, u16* Bs, f32x4 acc[4][4], int m0, int n0) {
  const int t = threadIdx.x;
  const int lane = t & 63, w = t >> 6;
  const int wr = (w >> 1) * 64, wc = (w & 1) * 64;  // wave sub-tile 64x64
  const int lr = lane & 15, g = lane >> 4;
  const int rr = t >> 2, c8 = (t & 3) * 8;          // staging row/chunk
#pragma unroll
  for (int mi = 0; mi < 4; ++mi)
#pragma unroll
    for (int ni = 0; ni < 4; ++ni)
      acc[mi][ni] = (f32x4){0.f, 0.f, 0.f, 0.f};
  const u16* ga0 = A  + (size_t)(m0 + rr) * D_MODEL + c8;
  const u16* ga1 = A  + (size_t)(m0 + 64 + rr) * D_MODEL + c8;
  const u16* gb0 = Bm + (size_t)(n0 + rr) * D_MODEL + c8;
  const u16* gb1 = Bm + (size_t)(n0 + 64 + rr) * D_MODEL + c8;
  // prologue: stage K-step 0 into buffer 0
  async_copy16(ga0, As + t * 8);
  async_copy16(ga1, As + 2048 + t * 8);
  async_copy16(gb0, Bs + t * 8);
  async_copy16(gb1, Bs + 2048 + t * 8);
  int cur = 0;
  for (int k0 = 0; k0 < D_MODEL; k0 += 32) {
    __syncthreads();  // vmcnt+lgkm drain: buf[cur] ready, buf[cur^1] free
    if (k0 + 32 < D_MODEL) {  // prefetch next K-step into the other buffer
      u16* Ad = As + (cur ^ 1) * 4096;
      u16* Bd = Bs + (cur ^ 1) * 4096;
      async_copy16(ga0 + k0 + 32, Ad + t * 8);
      async_copy16(ga1 + k0 + 32, Ad + 2048 + t * 8);
      async_copy16(gb0 + k0 + 32, Bd + t * 8);
      async_copy16(gb1 + k0 + 32, Bd + 2048 + t * 8);
    }
    const u16* Ab = As + cur * 4096;
    const u16* Bb = Bs + cur * 4096;
    bf16x8 af[4], bfr[4];
#pragma unroll
    for (int mi = 0; mi < 4; ++mi)
      af[mi] = *(const bf16x8*)(Ab + (wr + mi * 16 + lr) * 32 + g * 8);
#pragma unroll
    for (int ni = 0; ni < 4; ++ni)
      bfr[ni] = *(const bf16x8*)(Bb + (wc + ni * 16 + lr) * 32 + g * 8);
#pragma unroll
    for (int mi = 0; mi < 4; ++mi)
#pragma unroll
      for (int ni = 0; ni < 4; ++ni)
        acc[mi][ni] = __builtin_amdgcn_mfma_f32_16x16x32_bf16(
            af[mi], bfr[ni], acc[mi][ni], 0, 0, 0);
    cur ^= 1;
  }
}

// ---------------- fused QKV projection ------------------------------------
// Q,K written [b,h,s,d]; V written TRANSPOSED Vt[b,h,d,s] for k_attn's
// b64 V-fragment reads. Q pre-scaled by QK_SCALE.
__global__ __launch_bounds__(256) void k_gemm_qkv(
    const u16* __restrict__ xb, const u16* __restrict__ wqb,
    const u16* __restrict__ wkb, const u16* __restrict__ wvb,
    u16* __restrict__ Qo, u16* __restrict__ Ko, u16* __restrict__ Vt) {
  __shared__ u16 As[2 * 4096], Bs[2 * 4096];
  const int m0 = blockIdx.x * 128;
  const int n0g = blockIdx.y * 128;
  const int proj = n0g >> 10;       // 0,1,2
  const int n0 = n0g & 1023;
  const u16* Bm = (proj == 0) ? wqb : (proj == 1) ? wkb : wvb;
  const float scale = (proj == 0) ? QK_SCALE : 1.0f;
  f32x4 acc[4][4];
  gemm_core(xb, Bm, As, Bs, acc, m0, n0);
  const int t = threadIdx.x, lane = t & 63, w = t >> 6;
  const int wr = (w >> 1) * 64, wc = (w & 1) * 64;
  const int lr = lane & 15, g = lane >> 4;
  if (proj != 2) {
    u16* Out = (proj == 0) ? Qo : Ko;
#pragma unroll
    for (int mi = 0; mi < 4; ++mi)
#pragma unroll
      for (int ni = 0; ni < 4; ++ni)
#pragma unroll
        for (int jj = 0; jj < 4; ++jj) {
          int m = m0 + wr + mi * 16 + 4 * g + jj;    // (b,s)
          int cn = n0 + wc + ni * 16 + lr;           // (h,d)
          int h = cn >> 6, d = cn & 63;
          int b = m >> 11, s = m & 2047;
          Out[(((size_t)(b * NH + h) * SEQ) + s) * DH + d] =
              f2bf(acc[mi][ni][jj] * scale);
        }
  } else {
    // Vt[((b*NH+h)*DH + d)*SEQ + s], 4 consecutive s packed per 8B store
#pragma unroll
    for (int mi = 0; mi < 4; ++mi)
#pragma unroll
      for (int ni = 0; ni < 4; ++ni) {
        u16x4 pk;
#pragma unroll
        for (int jj = 0; jj < 4; ++jj) pk[jj] = f2bf(acc[mi][ni][jj]);
        int mb = m0 + wr + mi * 16 + 4 * g;          // s = mb + jj (mb % 4 == 0)
        int cn = n0 + wc + ni * 16 + lr;
        int h = cn >> 6, d = cn & 63;
        int b = mb >> 11, s = mb & 2047;
        *(u16x4*)(Vt + (((size_t)(b * NH + h) * DH + d) * SEQ) + s) = pk;
      }
  }
}

// ---------------- flash attention (causal) --------------------------------
// Round-14-verified structure. This round: (1) XCD-aware bh grouping —
// bid&7 selects a 4-head group so each XCD's L2 (4MB) holds exactly that
// group's K+V (4MB), turning staging loads into L2 hits; (2) s_setprio(1)
// around MFMA clusters (T5; attn multi-block regime, m191-positive).
__global__ __launch_bounds__(256, 4) void k_attn(
    const u16* __restrict__ Q, const u16* __restrict__ K,
    const u16* __restrict__ Vt, u16* __restrict__ att) {
  __shared__ u16 Ksh[2][4096];
  __shared__ u16 Vsh[2][4096];
  const int t = threadIdx.x, lane = t & 63, w = t >> 6;
  const int lr = lane & 15, g = lane >> 4;
  // XCD-grouped, 4-class balanced, heavy-first (bijective: 3+2+3+2 bits):
  // xcd = bid&7 -> bh in {4c..4c+3}; j4 top bits keep heavy classes first.
  const int bid = blockIdx.x;
  const int bh = (bid & 7) * 4 + ((bid >> 3) & 3);
  const int k4 = (bid >> 5) & 7;
  const int j4 = bid >> 8;
  const int qb = (j4 == 0) ? (31 - k4) : (j4 == 1) ? k4
               : (j4 == 2) ? (23 - k4) : (8 + k4);
  const int q0 = qb * 64, qw = q0 + w * 16;
  const size_t hb = (size_t)bh * SEQ * DH;
  const u16* Qp  = Q  + hb;
  const u16* Kp  = K  + hb;
  const u16* Vtp = Vt + hb;   // [d][s] layout

  // Q B-fragments: lane holds Q[qw+lr][kk*32+8g..+7]
  bf16x8 qfr[2];
#pragma unroll
  for (int kk = 0; kk < 2; ++kk)
    qfr[kk] = *(const bf16x8*)(Qp + (size_t)(qw + lr) * DH + kk * 32 + g * 8);

  f32x4 o[4];
#pragma unroll
  for (int d = 0; d < 4; ++d) o[d] = (f32x4){0.f, 0.f, 0.f, 0.f};
  f32x4 lacc = (f32x4){0.f, 0.f, 0.f, 0.f};   // l for q=qw+4g+jj (same idx as o)
  float mrow = -__builtin_inff();

  // all-ones B fragment for the l-accumulation MFMA
  const short one_bf = (short)0x3F80;
  const bf16x8 onesb = {one_bf, one_bf, one_bf, one_bf,
                        one_bf, one_bf, one_bf, one_bf};

  // pre-swizzled per-thread staging sources (linear LDS dest t*16)
  const int sswz = ((t & 7) * 16) ^ (((t >> 3) & 7) << 4);
  const char* srcK = (const char*)Kp + (t >> 3) * 128 + sswz;
  const char* srcV = (const char*)Vtp + (t >> 3) * 4096 + sswz;

  const int nkv = qb + 1;
  int cur = 0;

  // prologue: stage tile 0 into buffer 0 (two 4KB halves each)
  async_copy16(srcK,          (char*)&Ksh[0][0] + t * 16);
  async_copy16(srcK + 4096,   (char*)&Ksh[0][0] + 4096 + t * 16);
  async_copy16(srcV,          (char*)&Vsh[0][0] + t * 16);
  async_copy16(srcV + 131072, (char*)&Vsh[0][0] + 4096 + t * 16);

  for (int it = 0; it < nkv; ++it) {
    const int kv0 = it * 64;
    __syncthreads();  // vmcnt drain -> buf[cur] ready
    if (it + 1 < nkv) {
      const char* sk = srcK + (size_t)(it + 1) * 8192;
      const char* sv = srcV + (size_t)(it + 1) * 128;
      char* kd = (char*)&Ksh[cur ^ 1][0];
      char* vd = (char*)&Vsh[cur ^ 1][0];
      async_copy16(sk,          kd + t * 16);
      async_copy16(sk + 4096,   kd + 4096 + t * 16);
      async_copy16(sv,          vd + t * 16);
      async_copy16(sv + 131072, vd + 4096 + t * 16);
    }
    if (kv0 <= qw + 15) {  // wave-uniform causal early-out
      const char* kbase = (const char*)&Ksh[cur][0];
      const char* vbase = (const char*)&Vsh[cur][0];
      // K A-fragments (swizzled b128 reads), kv rows mf*16+lr
      bf16x8 kfr[4][2];
#pragma unroll
      for (int mf = 0; mf < 4; ++mf) {
        int row = mf * 16 + lr;
#pragma unroll
        for (int kk = 0; kk < 2; ++kk) {
          int off = (row * 128 + kk * 64 + g * 16) ^ ((row & 7) << 4);
          kfr[mf][kk] = *(const bf16x8*)(kbase + off);
        }
      }
      // S^T = K Q^T : rows kv (mf 0..3), col q = lr
      f32x4 st[4];
      __builtin_amdgcn_s_setprio(1);
#pragma unroll
      for (int mf = 0; mf < 4; ++mf) {
        f32x4 z = (f32x4){0.f, 0.f, 0.f, 0.f};
        z = __builtin_amdgcn_mfma_f32_16x16x32_bf16(kfr[mf][0], qfr[0], z, 0, 0, 0);
        st[mf] = __builtin_amdgcn_mfma_f32_16x16x32_bf16(kfr[mf][1], qfr[1], z, 0, 0, 0);
      }
      __builtin_amdgcn_s_setprio(0);
      if (kv0 + 63 > qw) {  // diagonal block: per-element causal mask
#pragma unroll
        for (int mf = 0; mf < 4; ++mf)
#pragma unroll
          for (int jj = 0; jj < 4; ++jj) {
            int kv = kv0 + mf * 16 + 4 * g + jj;
            st[mf][jj] = (kv > qw + lr) ? -__builtin_inff() : st[mf][jj];
          }
      }
      // tile max over kv for q = lr (max3-structured)
      float r1 = fmax3(st[0][0], st[0][1], st[0][2]);
      float r2 = fmax3(st[0][3], st[1][0], st[1][1]);
      float r3 = fmax3(st[1][2], st[1][3], st[2][0]);
      float r4 = fmax3(st[2][1], st[2][2], st[2][3]);
      float r5 = fmax3(st[3][0], st[3][1], st[3][2]);
      float v = fmax3(fmax3(r1, r2, r3), fmax3(r4, r5, st[3][3]),
                      -__builtin_inff());
      v = fmaxf(v, __shfl_xor(v, 16));
      v = fmaxf(v, __shfl_xor(v, 32));
      // defer-max (T13): rescale only if max grew by > 8 (exp2 domain)
      if (__any(v > mrow + 8.0f)) {
        float mnew = fmaxf(mrow, v);
        float fac = exp2_hw(mrow - mnew);
        mrow = mnew;
        float fq[4];
#pragma unroll
        for (int jj = 0; jj < 4; ++jj)
          fq[jj] = __shfl(fac, 4 * g + jj);
#pragma unroll
        for (int d = 0; d < 4; ++d)
#pragma unroll
          for (int jj = 0; jj < 4; ++jj)
            o[d][jj] *= fq[jj];
#pragma unroll
        for (int jj = 0; jj < 4; ++jj)
          lacc[jj] *= fq[jj];
      }
      // P = exp2(S - m) via raw v_exp_f32; bounded by 2^8 when deferred
      float p[4][4];
#pragma unroll
      for (int mf = 0; mf < 4; ++mf)
#pragma unroll
        for (int jj = 0; jj < 4; ++jj)
          p[mf][jj] = exp2_hw(st[mf][jj] - mrow);
      // P -> bf16 A-fragments via cvt_pk; slot m4*4+jj <- p[ks*2+m4][jj]
      bf16x8 pa[2];
#pragma unroll
      for (int ks = 0; ks < 2; ++ks) {
        union { bf16x8 v8; u32 wdz[4]; } pu;
        pu.wdz[0] = cvtpk(p[ks * 2][0],     p[ks * 2][1]);
        pu.wdz[1] = cvtpk(p[ks * 2][2],     p[ks * 2][3]);
        pu.wdz[2] = cvtpk(p[ks * 2 + 1][0], p[ks * 2 + 1][1]);
        pu.wdz[3] = cvtpk(p[ks * 2 + 1][2], p[ks * 2 + 1][3]);
        pa[ks] = pu.v8;
      }
      // l accumulation on the MFMA pipe: C[q][*] = sum_kv P (B = ones)
      __builtin_amdgcn_s_setprio(1);
      lacc = __builtin_amdgcn_mfma_f32_16x16x32_bf16(pa[0], onesb, lacc, 0, 0, 0);
      lacc = __builtin_amdgcn_mfma_f32_16x16x32_bf16(pa[1], onesb, lacc, 0, 0, 0);
      __builtin_amdgcn_s_setprio(0);
      // V B-fragments from Vt LDS: b64 reads, jj-contiguous
#pragma unroll
      for (int ks = 0; ks < 2; ++ks) {
        bf16x8 vb[4];
#pragma unroll
        for (int dd = 0; dd < 4; ++dd) {
          int row = dd * 16 + lr;
          int sz = (row & 7) << 4;
          union { bf16x8 v8; bf16x4 h[2]; } u;
          u.h[0] = *(const bf16x4*)(vbase + ((row * 128 + ks * 64 + g * 8) ^ sz));
          u.h[1] = *(const bf16x4*)(vbase + ((row * 128 + ks * 64 + 32 + g * 8) ^ sz));
          vb[dd] = u.v8;
        }
        __builtin_amdgcn_s_setprio(1);
#pragma unroll
        for (int dd = 0; dd < 4; ++dd)
          o[dd] = __builtin_amdgcn_mfma_f32_16x16x32_bf16(pa[ks], vb[dd], o[dd], 0, 0, 0);
        __builtin_amdgcn_s_setprio(0);
      }
    }
    cur ^= 1;
  }
  // epilogue: divide by l (lane-local), write att[b, q, h*64+d] bf16
  const int b = bh >> 4, h = bh & 15;
#pragma unroll
  for (int jj = 0; jj < 4; ++jj) {
    float li = 1.0f / lacc[jj];
    int q = qw + 4 * g + jj;
#pragma unroll
    for (int d = 0; d < 4; ++d) {
      int cn = h * 64 + d * 16 + lr;
      att[(size_t)(b * SEQ + q) * D_MODEL + cn] = f2bf(o[d][jj] * li);
    }
  }
}

// ---------------- output projection (fp32 out) ----------------------------
// 64x64 tiles, 4 blocks/CU, dbuf staging (round-14 structure).
__global__ __launch_bounds__(256, 4) void k_gemm_out(
    const u16* __restrict__ att, const u16* __restrict__ wob,
    float* __restrict__ out) {
  __shared__ u16 As[2 * 2048], Bs[2 * 2048];
  const int m0 = blockIdx.x * 64, n0 = blockIdx.y * 64;
  const int t = threadIdx.x, lane = t & 63, w = t >> 6;
  const int wr = (w >> 1) * 32, wc = (w & 1) * 32;  // wave sub-tile 32x32
  const int lr = lane & 15, g = lane >> 4;
  const int rr = t >> 2, c8 = (t & 3) * 8;
  f32x4 acc[2][2];
#pragma unroll
  for (int mi = 0; mi < 2; ++mi)
#pragma unroll
    for (int ni = 0; ni < 2; ++ni)
      acc[mi][ni] = (f32x4){0.f, 0.f, 0.f, 0.f};
  const u16* ga0 = att + (size_t)(m0 + rr) * D_MODEL + c8;
  const u16* gb0 = wob + (size_t)(n0 + rr) * D_MODEL + c8;
  // prologue: stage K-step 0 into buffer 0 (one copy16/thread per matrix)
  async_copy16(ga0, As + t * 8);
  async_copy16(gb0, Bs + t * 8);
  int cur = 0;
  for (int k0 = 0; k0 < D_MODEL; k0 += 32) {
    __syncthreads();
    if (k0 + 32 < D_MODEL) {
      async_copy16(ga0 + k0 + 32, As + (cur ^ 1) * 2048 + t * 8);
      async_copy16(gb0 + k0 + 32, Bs + (cur ^ 1) * 2048 + t * 8);
    }
    const u16* Ab = As + cur * 2048;
    const u16* Bb = Bs + cur * 2048;
    bf16x8 af[2], bfr[2];
#pragma unroll
    for (int mi = 0; mi < 2; ++mi)
      af[mi] = *(const bf16x8*)(Ab + (wr + mi * 16 + lr) * 32 + g * 8);
#pragma unroll
    for (int ni = 0; ni < 2; ++ni)
      bfr[ni] = *(const bf16x8*)(Bb + (wc + ni * 16 + lr) * 32 + g * 8);
#pragma unroll
    for (int mi = 0; mi < 2; ++mi)
#pragma unroll
      for (int ni = 0; ni < 2; ++ni)
        acc[mi][ni] = __builtin_amdgcn_mfma_f32_16x16x32_bf16(
            af[mi], bfr[ni], acc[mi][ni], 0, 0, 0);
    cur ^= 1;
  }
#pragma unroll
  for (int mi = 0; mi < 2; ++mi)
#pragma unroll
    for (int ni = 0; ni < 2; ++ni)
#pragma unroll
      for (int jj = 0; jj < 4; ++jj) {
        int m = m0 + wr + mi * 16 + 4 * g + jj;
        int n = n0 + wc + ni * 16 + lr;
        out[(size_t)m * D_MODEL + n] = acc[mi][ni][jj];
      }
}

extern "C" void kernel_launch(void* const* d_in, const int* in_sizes, int n_in,
                              void* d_out, int out_size, void* d_ws, size_t ws_size,
                              hipStream_t stream) {
  (void)in_sizes; (void)n_in; (void)out_size; (void)ws_size;
  const float* x  = (const float*)d_in[0];
  const float* WQ = (const float*)d_in[1];
  const float* WK = (const float*)d_in[2];
  const float* WV = (const float*)d_in[3];
  const float* WO = (const float*)d_in[4];
  float* out = (float*)d_out;
  char* ws = (char*)d_ws;
  u16* xb  = (u16*)(ws);
  u16* wqb = (u16*)(ws + ((size_t)8 << 20));
  u16* wkb = (u16*)(ws + ((size_t)10 << 20));
  u16* wvb = (u16*)(ws + ((size_t)12 << 20));
  u16* wob = (u16*)(ws + ((size_t)14 << 20));
  u16* Qb  = (u16*)(ws + ((size_t)16 << 20));
  u16* Kb  = (u16*)(ws + ((size_t)24 << 20));
  u16* Vtb = (u16*)(ws + ((size_t)32 << 20));
  u16* att = (u16*)(ws + ((size_t)40 << 20));

  hipLaunchKernelGGL(k_convert, dim3(4096), dim3(256), 0, stream,
                     x, WQ, WK, WV, WO, xb, wqb, wkb, wvb, wob);
  hipLaunchKernelGGL(k_gemm_qkv, dim3(32, 24), dim3(256), 0, stream,
                     xb, wqb, wkb, wvb, Qb, Kb, Vtb);
  hipLaunchKernelGGL(k_attn, dim3(1024), dim3(256), 0, stream,
                     Qb, Kb, Vtb, att);
  hipLaunchKernelGGL(k_gemm_out, dim3(64, 16), dim3(256), 0, stream,
                     att, wob, out);
}